// Round 1
// baseline (1250.497 us; speedup 1.0000x reference)
//
#include <hip/hip_runtime.h>
#include <math.h>

// Problem constants (fixed by reference setup)
#define NN 50000
#define EE 400000
#define CINV 32
#define KKEEP 25000          // ceil(0.5*N)
#define SEQL 5
#define HASH_BITS 20
#define HASH_SIZE (1u<<HASH_BITS)
#define HASH_MASK (HASH_SIZE-1u)
#define HEMPTY 0xFFFFFFFFu
#define PSB 196              // ceil(NN/256)

typedef float vf4 __attribute__((ext_vector_type(4)));

__device__ __forceinline__ float sigm(float x){ return __builtin_amdgcn_rcpf(1.f+__expf(-x)); }
__device__ __forceinline__ float ftanh(float x){ return 1.f - 2.f*__builtin_amdgcn_rcpf(1.f+__expf(2.f*x)); }

// ---------------- merged init (+ LSTM weight prep) ----------------
// WT*:  W_ih^T laid out [k][r] for k_xw's LDS tile.
// WHT*: W_hh pre-transposed for k_rec's in-register layout:
//       vf4 element [(kq*4+g)*64 + ch] = whh[g*64+ch][4kq..4kq+3]
__global__ void k_init(uint2* __restrict__ hash, unsigned* __restrict__ hist,
                       int* __restrict__ degcnt, int* __restrict__ diagint,
                       int* __restrict__ fillc, int* __restrict__ minv,
                       unsigned* scal, unsigned long long* selp,
                       const float* __restrict__ w0, const float* __restrict__ b0i,
                       const float* __restrict__ b0h, const float* __restrict__ wf,
                       const float* __restrict__ bfi, const float* __restrict__ bfh,
                       const float* __restrict__ whh0, const float* __restrict__ whhf,
                       float* __restrict__ WT0, float* __restrict__ WTf,
                       float* __restrict__ WHT0, float* __restrict__ WHTf,
                       float* __restrict__ bs0, float* __restrict__ bsf){
  int i = blockIdx.x*256 + threadIdx.x;
  if (i < (int)HASH_SIZE) hash[i] = make_uint2(HEMPTY, 0u);
  if (i < 4*65536) hist[i] = 0u;
  if (i < NN){ degcnt[i]=0; diagint[i]=0; fillc[i]=0; minv[i]=-1; }
  if (i < 256*64){
    int r = i>>6, k = i&63;
    WT0[k*256+r] = w0[i];
    WTf[k*256+r] = wf[i];
    int dst = (((k>>2)*4 + (r>>6))*64 + (r&63))*4 + (k&3);
    WHT0[dst] = whh0[i];
    WHTf[dst] = whhf[i];
  }
  if (i < 256){ bs0[i]=b0i[i]+b0h[i]; bsf[i]=bfi[i]+bfh[i]; }
  if (i == 0){ scal[0]=0u; scal[1]=0u; scal[3]=KKEEP; selp[0]=0ull; }
}

// ---------------- phase2: degcnt + hash build + mask detect + GCN0 matmul ----------------
// (edge work and the independent x@W0 matmul merged into one launch)
__global__ void k_phase2(const int* __restrict__ row, const int* __restrict__ col,
                         const int* __restrict__ mp, int* __restrict__ degcnt,
                         uint2* __restrict__ tab, unsigned* scal,
                         const float* __restrict__ X, const float* __restrict__ W,
                         float* __restrict__ Y){
  int idx = blockIdx.x*256 + threadIdx.x;
  if (idx < EE){
    int c = col[idx];
    atomicAdd(&degcnt[c], 1);
    unsigned key = (unsigned)row[idx]*50000u + (unsigned)c;
    unsigned h = (key*2654435761u) >> (32-HASH_BITS);
    for(;;){
      unsigned old = atomicCAS(&tab[h].x, HEMPTY, key);
      if (old==HEMPTY || old==key){ atomicAdd(&tab[h].y, 1u); break; }
      h = (h+1)&HASH_MASK;
    }
  }
  if (idx < NN/4){ if ((unsigned)mp[idx] > 1u) atomicOr(&scal[1], 1u); }
  if (idx < NN*16){
    int i = idx>>4, fq = idx&15;
    const vf4* X4 = (const vf4*)&X[i*CINV];
    const vf4* W4 = (const vf4*)W;
    vf4 acc = {0.f,0.f,0.f,0.f};
    #pragma unroll
    for (int kq=0;kq<CINV/4;kq++){
      vf4 xv = X4[kq];
      #pragma unroll
      for (int u=0;u<4;u++) acc += xv[u] * W4[(kq*4+u)*16+fq];
    }
    ((vf4*)Y)[i*16+fq] = acc;
  }
}

// ---------------- prefix sum (indptr) + dinv0 ----------------
__global__ void k_psum1(const int* __restrict__ deg, int* __restrict__ part,
                        int* __restrict__ bsum, float* __restrict__ dinv){
  __shared__ int sc[256];
  int b = blockIdx.x, t = threadIdx.x, i = b*256+t;
  int v = (i<NN) ? deg[i] : 0;
  if (i < NN) dinv[i] = rsqrtf((float)v + 2.0f);
  sc[t] = v; __syncthreads();
  for (int o=1;o<256;o<<=1){
    int x = (t>=o) ? sc[t-o] : 0;
    __syncthreads();
    sc[t] += x;
    __syncthreads();
  }
  if (i < NN) part[i] = sc[t]-v;
  if (t == 255) bsum[b] = sc[255];
}
// psum3 with per-block redundant scan of bsum (kills the separate psum2 launch)
__global__ void k_psum3(const int* __restrict__ part, const int* __restrict__ bsum,
                        int* __restrict__ indptr){
  __shared__ int sc[256];
  int t = threadIdx.x;
  int v = (t<PSB) ? bsum[t] : 0;
  sc[t] = v; __syncthreads();
  for (int o=1;o<256;o<<=1){
    int x = (t>=o) ? sc[t-o] : 0;
    __syncthreads();
    sc[t] += x;
    __syncthreads();
  }
  int bb = blockIdx.x;
  int ex = sc[bb] - ((bb<PSB) ? bsum[bb] : 0);   // exclusive prefix for this block
  int i = bb*256 + t;
  if (i < NN) indptr[i] = part[i] + ex;
  if (i == 0) indptr[NN] = EE;
}

// ---------------- csr fill + A^2 diag + mask compact ----------------
__global__ void k_phase4(const int* __restrict__ row, const int* __restrict__ col,
                         const int* __restrict__ indptr, int* __restrict__ fillc,
                         int* __restrict__ csr_r, const uint2* __restrict__ tab,
                         int* __restrict__ diagint, const void* __restrict__ mp,
                         unsigned* scal, int* __restrict__ mlist, int* __restrict__ minv){
  int idx = blockIdx.x*256 + threadIdx.x;
  if (idx < EE){
    int r = row[idx], c = col[idx];
    int pos = indptr[c] + atomicAdd(&fillc[c], 1);
    csr_r[pos] = r;
    unsigned rkey = (unsigned)c*50000u + (unsigned)r;
    unsigned h = (rkey*2654435761u) >> (32-HASH_BITS);
    for(;;){
      unsigned kk = tab[h].x;
      if (kk==rkey){ atomicAdd(&diagint[r], (int)tab[h].y); break; }
      if (kk==HEMPTY) break;
      h = (h+1)&HASH_MASK;
    }
  } else {
    int i = idx - EE;
    if (i < NN){
      int mv = scal[1] ? (int)((const unsigned char*)mp)[i] : ((const int*)mp)[i];
      if (mv){ int p = (int)atomicAdd(&scal[0], 1u); mlist[p] = i; minv[i] = p; }
    }
  }
}

// ---------------- remaining matmul (up-GCN input) ----------------
__global__ void k_mm64v(const float* __restrict__ X, const float* __restrict__ W, float* __restrict__ Y){
  int idx = blockIdx.x*256 + threadIdx.x;
  if (idx >= NN*16) return;
  int i = idx>>4, fq = idx&15;
  const vf4* X4 = (const vf4*)&X[i*64];
  const vf4* W4 = (const vf4*)W;
  vf4 acc = {0.f,0.f,0.f,0.f};
  #pragma unroll
  for (int kq=0;kq<16;kq++){
    vf4 xv = X4[kq];
    #pragma unroll
    for (int u=0;u<4;u++) acc += xv[u] * W4[(kq*4+u)*16+fq];
  }
  ((vf4*)Y)[i*16+fq] = acc;
}

// ---------------- CSR gather GCN kernels (wave per node, shuffle-pipelined) ----------------
__global__ void g_gcn0(const int* __restrict__ indptr, const int* __restrict__ csr_r,
                       const float* __restrict__ dinv, const float* __restrict__ H,
                       const float* __restrict__ b, const float* __restrict__ pw,
                       float* __restrict__ out, unsigned long long* __restrict__ keys,
                       float* __restrict__ score, unsigned* __restrict__ hist){
  int node = blockIdx.x*4 + (threadIdx.x>>6), lane = threadIdx.x&63;
  if (node >= NN) return;
  int s = __builtin_amdgcn_readfirstlane(indptr[node]);
  int e = __builtin_amdgcn_readfirstlane(indptr[node+1]);
  int deg = e - s;
  float a0=0.f,a1=0.f,a2=0.f,a3=0.f;
  for (int base=0; base<deg; base+=64){
    int take = min(64, deg-base);
    bool act = lane < take;
    int ii = act ? csr_r[s+base+lane] : 0;
    float dv = act ? dinv[ii] : 0.f;
    int j=0;
    for (; j+4<=take; j+=4){
      int r0=__shfl(ii,j,64), r1=__shfl(ii,j+1,64), r2=__shfl(ii,j+2,64), r3=__shfl(ii,j+3,64);
      float d0=__shfl(dv,j,64), d1=__shfl(dv,j+1,64), d2=__shfl(dv,j+2,64), d3=__shfl(dv,j+3,64);
      a0 += d0*H[(size_t)r0*64+lane];
      a1 += d1*H[(size_t)r1*64+lane];
      a2 += d2*H[(size_t)r2*64+lane];
      a3 += d3*H[(size_t)r3*64+lane];
    }
    for (; j<take; j++){
      int r0=__shfl(ii,j,64); float d0=__shfl(dv,j,64);
      a0 += d0*H[(size_t)r0*64+lane];
    }
  }
  float acc = (a0+a1)+(a2+a3);
  float di = dinv[node];
  float v = di*acc + 2.f*di*di*H[(size_t)node*64+lane] + b[lane];
  float x1v = fmaxf(v, 0.f);
  out[(size_t)node*64+lane] = x1v;
  // fused TopK score: s = tanh((x1 . pw)/||pw||)
  float pv = pw[lane];
  float nq = pv*pv;
  float dq = x1v*pv;
  for (int o=32;o;o>>=1){ nq += __shfl_down(nq, o, 64); dq += __shfl_down(dq, o, 64); }
  if (lane==0){
    float sv = tanhf(dq / sqrtf(nq));
    sv = sv + 0.0f;               // canonicalize -0 -> +0
    score[node] = sv;
    unsigned u = __float_as_uint(sv);
    unsigned asc = (u>>31) ? ~u : (u | 0x80000000u);
    unsigned desc = ~asc;
    keys[node] = (((unsigned long long)desc)<<32) | (unsigned)node;
    atomicAdd(&hist[desc>>16], 1u);      // radix round-0 histogram
  }
}
__global__ void g_t2(const int* __restrict__ indptr, const int* __restrict__ csr_r,
                     const float* __restrict__ dinv1, const float* __restrict__ hp,
                     float* __restrict__ t2){
  int node = blockIdx.x*4 + (threadIdx.x>>6), lane = threadIdx.x&63;
  if (node >= NN) return;
  int s = __builtin_amdgcn_readfirstlane(indptr[node]);
  int e = __builtin_amdgcn_readfirstlane(indptr[node+1]);
  int deg = e - s;
  float a0 = dinv1[node]*hp[(size_t)node*64+lane];   // self loop
  float a1 = 0.f;
  for (int base=0; base<deg; base+=64){
    int take = min(64, deg-base);
    bool act = lane < take;
    int ii = act ? csr_r[s+base+lane] : 0;
    float dv = act ? dinv1[ii] : 0.f;
    int j=0;
    for (; j+2<=take; j+=2){
      float d0=__shfl(dv,j,64), d1=__shfl(dv,j+1,64);
      int r0=__shfl(ii,j,64), r1=__shfl(ii,j+1,64);
      if (d0!=0.f) a0 += d0*hp[(size_t)r0*64+lane];
      if (d1!=0.f) a1 += d1*hp[(size_t)r1*64+lane];
    }
    for (; j<take; j++){
      float d0=__shfl(dv,j,64); int r0=__shfl(ii,j,64);
      if (d0!=0.f) a0 += d0*hp[(size_t)r0*64+lane];
    }
  }
  t2[(size_t)node*64+lane] = a0+a1;
}
// D[i] = (masked ? H0[minv[i]] : C[i]) + (kept ? relu(x2_i) : 0)
__global__ void g_agg2y(const int* __restrict__ indptr, const int* __restrict__ csr_r,
                        const float* __restrict__ t2, const float* __restrict__ hp,
                        const float* __restrict__ dinv1, const int* __restrict__ diagint,
                        const int* __restrict__ kp, const float* __restrict__ b1,
                        const float* __restrict__ C, const float* __restrict__ Hbuf,
                        const int* __restrict__ minv, float* __restrict__ D){
  int node = blockIdx.x*4 + (threadIdx.x>>6), lane = threadIdx.x&63;
  if (node >= NN) return;
  int mv = minv[node];
  float base = (mv >= 0) ? Hbuf[(size_t)mv*64+lane] : C[(size_t)node*64+lane];
  float add = 0.f;
  if (kp[node]){
    int s = __builtin_amdgcn_readfirstlane(indptr[node]);
    int e = __builtin_amdgcn_readfirstlane(indptr[node+1]);
    int deg = e - s;
    float a0 = t2[(size_t)node*64+lane];             // self loop
    float a1=0.f,a2=0.f,a3=0.f;
    for (int bs2=0; bs2<deg; bs2+=64){
      int take = min(64, deg-bs2);
      bool act = lane < take;
      int ii = act ? csr_r[s+bs2+lane] : 0;
      int j=0;
      for (; j+4<=take; j+=4){
        int r0=__shfl(ii,j,64), r1=__shfl(ii,j+1,64), r2=__shfl(ii,j+2,64), r3=__shfl(ii,j+3,64);
        a0 += t2[(size_t)r0*64+lane];
        a1 += t2[(size_t)r1*64+lane];
        a2 += t2[(size_t)r2*64+lane];
        a3 += t2[(size_t)r3*64+lane];
      }
      for (; j<take; j++){
        int r0=__shfl(ii,j,64);
        a0 += t2[(size_t)r0*64+lane];
      }
    }
    float acc = (a0+a1)+(a2+a3);
    float di = dinv1[node], hv = hp[(size_t)node*64+lane];
    float diag = (float)(diagint[node] + 1);
    float v = di*(acc - diag*di*hv) + 2.f*di*di*hv + b1[lane];
    add = fmaxf(v, 0.f);
  }
  D[(size_t)node*64+lane] = base + add;
}
__global__ void g_up(const int* __restrict__ indptr, const int* __restrict__ csr_r,
                     const float* __restrict__ dinv, const float* __restrict__ H,
                     const float* __restrict__ b, float* __restrict__ xo, float* __restrict__ out){
  int node = blockIdx.x*4 + (threadIdx.x>>6), lane = threadIdx.x&63;
  if (node >= NN) return;
  int s = __builtin_amdgcn_readfirstlane(indptr[node]);
  int e = __builtin_amdgcn_readfirstlane(indptr[node+1]);
  int deg = e - s;
  float a0=0.f,a1=0.f,a2=0.f,a3=0.f;
  for (int base=0; base<deg; base+=64){
    int take = min(64, deg-base);
    bool act = lane < take;
    int ii = act ? csr_r[s+base+lane] : 0;
    float dv = act ? dinv[ii] : 0.f;
    int j=0;
    for (; j+4<=take; j+=4){
      int r0=__shfl(ii,j,64), r1=__shfl(ii,j+1,64), r2=__shfl(ii,j+2,64), r3=__shfl(ii,j+3,64);
      float d0=__shfl(dv,j,64), d1=__shfl(dv,j+1,64), d2=__shfl(dv,j+2,64), d3=__shfl(dv,j+3,64);
      a0 += d0*H[(size_t)r0*64+lane];
      a1 += d1*H[(size_t)r1*64+lane];
      a2 += d2*H[(size_t)r2*64+lane];
      a3 += d3*H[(size_t)r3*64+lane];
    }
    for (; j<take; j++){
      int r0=__shfl(ii,j,64); float d0=__shfl(dv,j,64);
      a0 += d0*H[(size_t)r0*64+lane];
    }
  }
  float acc = (a0+a1)+(a2+a3);
  float di = dinv[node];
  float v = di*acc + 2.f*di*di*H[(size_t)node*64+lane] + b[lane];
  xo[(size_t)node*64+lane] = v; out[(size_t)node*64+lane] = v;
}

// ---------------- TopK radix select (round 0 hist fused into g_gcn0) ----------------
__global__ void k_hist(const unsigned long long* __restrict__ keys, unsigned* __restrict__ hist,
                       const unsigned long long* __restrict__ selp, int round){
  int i = blockIdx.x*256 + threadIdx.x;
  if (i >= NN) return;
  unsigned long long key = keys[i];
  int shift = 48 - 16*round;
  if ((key>>(shift+16)) == selp[0])
    atomicAdd(&hist[(unsigned)((key>>shift)&0xFFFFull)], 1u);
}
__global__ void k_pick(const unsigned* __restrict__ hist, unsigned long long* selp, unsigned* scal){
  __shared__ unsigned csum[256];
  __shared__ unsigned bins[256];
  __shared__ int schunk;
  int t = threadIdx.x;
  const uint4* h4 = (const uint4*)(hist + t*256);
  unsigned s = 0;
  #pragma unroll 8
  for (int j=0;j<64;j++){ uint4 v = h4[j]; s += v.x+v.y+v.z+v.w; }
  csum[t] = s;
  __syncthreads();
  if (t==0){
    unsigned rem = scal[3];
    int chunk = 255;
    for (int c2=0;c2<256;c2++){ unsigned cc=csum[c2]; if (rem>cc) rem-=cc; else { chunk=c2; break; } }
    schunk = chunk; scal[3] = rem;
  }
  __syncthreads();
  bins[t] = hist[schunk*256 + t];
  __syncthreads();
  if (t==0){
    unsigned rem = scal[3];
    int bin = schunk*256 + 255;
    for (int b=0;b<256;b++){ unsigned hv=bins[b]; if (rem>hv) rem-=hv; else { bin = schunk*256 + b; break; } }
    selp[0] = (selp[0]<<16) | (unsigned long long)(unsigned)bin;
    scal[3] = rem;
  }
}
// pooled degree pass 1 (CSR gather): kp[i]; ts[i] = sum_{r->i} kp[r] + kp[i]
__global__ void k_tsg(const int* __restrict__ indptr, const int* __restrict__ csr_r,
                      const unsigned long long* __restrict__ keys,
                      const unsigned long long* __restrict__ selp,
                      int* __restrict__ kp, int* __restrict__ ts){
  int i = blockIdx.x*256 + threadIdx.x;
  if (i >= NN) return;
  unsigned long long sp = selp[0];
  int s = indptr[i], e = indptr[i+1];
  int self = (keys[i] <= sp) ? 1 : 0;
  kp[i] = self;
  int acc = self;
  for (int j=s;j<e;j++) acc += (keys[csr_r[j]] <= sp) ? 1 : 0;
  ts[i] = acc;
}
// pooled degree pass 2 + dinv1 MERGED with hp = (x1*score)@W1 (both depend only on tsg)
__global__ void k_csgmm(const int* __restrict__ indptr, const int* __restrict__ csr_r,
                        const int* __restrict__ ts, const int* __restrict__ diagint,
                        const int* __restrict__ kp, float* __restrict__ dinv1,
                        const float* __restrict__ X, const float* __restrict__ W,
                        const float* __restrict__ sc, float* __restrict__ Y){
  int idx = blockIdx.x*256 + threadIdx.x;
  if (idx < NN*16){
    int i = idx>>4, fq = idx&15;
    if (!kp[i]) return;
    const vf4* X4 = (const vf4*)&X[i*64];
    const vf4* W4 = (const vf4*)W;
    vf4 acc = {0.f,0.f,0.f,0.f};
    #pragma unroll
    for (int kq=0;kq<16;kq++){
      vf4 xv = X4[kq];
      #pragma unroll
      for (int u=0;u<4;u++) acc += xv[u] * W4[(kq*4+u)*16+fq];
    }
    acc *= sc[i];
    ((vf4*)Y)[i*16+fq] = acc;
  } else {
    int i = idx - NN*16;
    if (i >= NN) return;
    int s = indptr[i], e = indptr[i+1];
    int acc = ts[i];
    for (int j=s;j<e;j++) acc += ts[csr_r[j]];
    dinv1[i] = kp[i] ? rsqrtf((float)(acc - diagint[i] - 1) + 2.0f) : 0.f;
  }
}

// ---------------- LSTM part 1: XW[n] = src[n] @ W_ih^T + (b_ih+b_hh) ----------------
__global__ __launch_bounds__(256) void k_xw(const float* __restrict__ src,
        const float* __restrict__ WT, const float* __restrict__ bsum,
        float* __restrict__ XW){
  __shared__ vf4 Wl[4096];              // 64 KB: WT[k][g] as vf4[(k*4+u)*64+fq]
  int t = threadIdx.x;
  const vf4* Wg = (const vf4*)WT;
  for (int u=t; u<4096; u+=256) Wl[u] = Wg[u];
  int fq = t & 63, wv = t >> 6;
  vf4 bias = ((const vf4*)bsum)[fq];
  __syncthreads();
  for (int g = blockIdx.x*4 + wv; g < NN/4; g += gridDim.x*4){
    int n0 = g*4;
    const vf4* X4 = (const vf4*)&src[(size_t)n0*64];   // 4 rows x 16 vf4
    vf4 a0=bias, a1=bias, a2=bias, a3=bias;
    #pragma unroll 4
    for (int kq=0;kq<16;kq++){
      vf4 x0 = X4[kq], x1 = X4[16+kq], x2 = X4[32+kq], x3 = X4[48+kq];
      vf4 w0 = Wl[(kq*4+0)*64+fq];
      vf4 w1 = Wl[(kq*4+1)*64+fq];
      vf4 w2 = Wl[(kq*4+2)*64+fq];
      vf4 w3 = Wl[(kq*4+3)*64+fq];
      a0 += x0.x*w0 + x0.y*w1 + x0.z*w2 + x0.w*w3;
      a1 += x1.x*w0 + x1.y*w1 + x1.z*w2 + x1.w*w3;
      a2 += x2.x*w0 + x2.y*w1 + x2.z*w2 + x2.w*w3;
      a3 += x3.x*w0 + x3.y*w1 + x3.z*w2 + x3.w*w3;
    }
    vf4* Y = (vf4*)XW;
    Y[(size_t)n0*64 + fq]       = a0;
    Y[(size_t)n0*64 + 64 + fq]  = a1;
    Y[(size_t)n0*64 + 128 + fq] = a2;
    Y[(size_t)n0*64 + 192 + fq] = a3;
  }
}

// ---------------- LSTM part 2: recurrence, wave-independent, zero barriers ----------------
// NEW (R10): each lane permanently holds the 4 W_hh rows it needs
// (r = g*64+lane, i.e. the i/f/g/o gates of channel `lane`) = 256 VGPRs of
// weights in the unified gfx950 register file. One wave runs 2 nodes'
// entire recurrence with NO __syncthreads: h is exchanged within-wave via a
// 256B LDS buffer read with uniform-address (broadcast) ds_read_b128, ordered
// by an explicit lgkmcnt(0). Gates never leave registers. Persistent grid:
// 256 blocks x 256 thr = 1024 waves (1 wave/SIMD at ~340 VGPR), ~12 tasks/wave.
__global__ __launch_bounds__(256, 1) void k_rec(const float* __restrict__ XW,
        const float* __restrict__ WHT, const float* __restrict__ bsum,
        const int* __restrict__ mlist, const unsigned* __restrict__ scal,
        float* __restrict__ dst, int scatter){
  int M = (int)scal[0];
  if (M < 0 || M > NN) M = 0;          // defensive (rocprof replay poisons scal)
  int w = threadIdx.x>>6, lane = threadIdx.x&63;
  // weight fill: 64 coalesced b128 loads (WHT pre-transposed in k_init)
  vf4 wr[64];
  const vf4* WT4 = (const vf4*)WHT;
  #pragma unroll
  for (int j=0;j<64;j++) wr[j] = WT4[j*64 + lane];
  __shared__ __align__(16) float sh[4][2][64];
  float* shA = &sh[w][0][0];
  float* shB = &sh[w][1][0];
  float b0v = bsum[lane], b1v = bsum[64+lane], b2v = bsum[128+lane], b3v = bsum[192+lane];
  int ntask = (M+7)>>3;
  for (int task = blockIdx.x; task < ntask; task += gridDim.x){
    int mA = task*8 + w*2, mB = mA + 1;
    bool vA = (mA < M), vB = (mB < M);
    int nodeA = mlist[vA ? mA : 0]; nodeA = min(max(nodeA,0),NN-1);
    int nodeB = mlist[vB ? mB : 0]; nodeB = min(max(nodeB,0),NN-1);
    float cA,hA,cB,hB;
    float xA0,xA1,xA2,xA3, xB0,xB1,xB2,xB3;
    {   // t = 0: h==0, gates = XW row (bias-only if left-padded)
      int rA = nodeA - (SEQL-1), rB = nodeB - (SEQL-1);
      if (rA >= 0){ const float* p=&XW[(size_t)rA*256]; xA0=p[lane];xA1=p[64+lane];xA2=p[128+lane];xA3=p[192+lane]; }
      else { xA0=b0v;xA1=b1v;xA2=b2v;xA3=b3v; }
      if (rB >= 0){ const float* p=&XW[(size_t)rB*256]; xB0=p[lane];xB1=p[64+lane];xB2=p[128+lane];xB3=p[192+lane]; }
      else { xB0=b0v;xB1=b1v;xB2=b2v;xB3=b3v; }
      cA = sigm(xA0)*ftanh(xA2); hA = sigm(xA3)*ftanh(cA);
      cB = sigm(xB0)*ftanh(xB2); hB = sigm(xB3)*ftanh(cB);
      shA[lane] = hA; shB[lane] = hB;
    }
    for (int t=1;t<SEQL;t++){
      // prefetch this timestep's gate-x rows (consumed after the matvec)
      int rA = nodeA - (SEQL-1) + t, rB = nodeB - (SEQL-1) + t;
      if (rA >= 0){ const float* p=&XW[(size_t)rA*256]; xA0=p[lane];xA1=p[64+lane];xA2=p[128+lane];xA3=p[192+lane]; }
      else { xA0=b0v;xA1=b1v;xA2=b2v;xA3=b3v; }
      if (rB >= 0){ const float* p=&XW[(size_t)rB*256]; xB0=p[lane];xB1=p[64+lane];xB2=p[128+lane];xB3=p[192+lane]; }
      else { xB0=b0v;xB1=b1v;xB2=b2v;xB3=b3v; }
      // same-wave LDS RAW: wait for our h writes, then broadcast-read
      asm volatile("s_waitcnt lgkmcnt(0)" ::: "memory");
      __builtin_amdgcn_sched_barrier(0);
      vf4 aA0={0,0,0,0},aA1={0,0,0,0},aA2={0,0,0,0},aA3={0,0,0,0};
      vf4 aB0={0,0,0,0},aB1={0,0,0,0},aB2={0,0,0,0},aB3={0,0,0,0};
      #pragma unroll
      for (int kq=0;kq<16;kq++){
        vf4 ha = *(const vf4*)&shA[kq*4];
        vf4 hb = *(const vf4*)&shB[kq*4];
        aA0 += ha*wr[kq*4+0]; aA1 += ha*wr[kq*4+1]; aA2 += ha*wr[kq*4+2]; aA3 += ha*wr[kq*4+3];
        aB0 += hb*wr[kq*4+0]; aB1 += hb*wr[kq*4+1]; aB2 += hb*wr[kq*4+2]; aB3 += hb*wr[kq*4+3];
      }
      float gAi = aA0.x+aA0.y+aA0.z+aA0.w + xA0;
      float gAf = aA1.x+aA1.y+aA1.z+aA1.w + xA1;
      float gAg = aA2.x+aA2.y+aA2.z+aA2.w + xA2;
      float gAo = aA3.x+aA3.y+aA3.z+aA3.w + xA3;
      cA = sigm(gAf)*cA + sigm(gAi)*ftanh(gAg);
      hA = sigm(gAo)*ftanh(cA);
      float gBi = aB0.x+aB0.y+aB0.z+aB0.w + xB0;
      float gBf = aB1.x+aB1.y+aB1.z+aB1.w + xB1;
      float gBg = aB2.x+aB2.y+aB2.z+aB2.w + xB2;
      float gBo = aB3.x+aB3.y+aB3.z+aB3.w + xB3;
      cB = sigm(gBf)*cB + sigm(gBi)*ftanh(gBg);
      hB = sigm(gBo)*ftanh(cB);
      if (t < SEQL-1){ shA[lane] = hA; shB[lane] = hB; }
    }
    if (vA){ size_t o = scatter ? ((size_t)nodeA*64 + lane) : ((size_t)mA*64 + lane); dst[o] = hA; }
    if (vB){ size_t o = scatter ? ((size_t)nodeB*64 + lane) : ((size_t)mB*64 + lane); dst[o] = hB; }
  }
}

// ==========================================================================
extern "C" void kernel_launch(void* const* d_in, const int* in_sizes, int n_in,
                              void* d_out, int out_size, void* d_ws, size_t ws_size,
                              hipStream_t stream) {
  const float* x   = (const float*)d_in[0];
  const int*   ei  = (const int*)d_in[1];
  const int*   row = ei;
  const int*   col = ei + EE;
  const void*  mp  = d_in[2];
  const float* W0  = (const float*)d_in[3];
  const float* b0  = (const float*)d_in[4];
  const float* W1  = (const float*)d_in[5];
  const float* b1  = (const float*)d_in[6];
  const float* pw  = (const float*)d_in[7];
  const float* Wu  = (const float*)d_in[8];
  const float* bu  = (const float*)d_in[9];
  const float* l0wih=(const float*)d_in[10];
  const float* l0whh=(const float*)d_in[11];
  const float* l0bih=(const float*)d_in[12];
  const float* l0bhh=(const float*)d_in[13];
  const float* lfwih=(const float*)d_in[14];
  const float* lfwhh=(const float*)d_in[15];
  const float* lfbih=(const float*)d_in[16];
  const float* lfbhh=(const float*)d_in[17];

  char* wp = (char*)d_ws;
  auto alloc = [&](size_t bytes)->char*{ char* p = wp; wp += ((bytes+255)/256)*256; return p; };
  float* A     = (float*)alloc((size_t)NN*64*4);   // h0 -> t2
  float* B     = (float*)alloc((size_t)NN*64*4);   // xo
  float* C     = (float*)alloc((size_t)NN*64*4);   // x1
  float* D     = (float*)alloc((size_t)NN*64*4);   // y
  float* Ebuf  = (float*)alloc((size_t)NN*64*4);   // hp -> up-GCN input
  float* Hbuf  = (float*)alloc((size_t)NN*64*4);   // LSTM0 compact output
  float* XW    = (float*)alloc((size_t)NN*256*4);  // gate-x precompute (51.2 MB)
  float* WT0   = (float*)alloc((size_t)256*64*4);
  float* WTf   = (float*)alloc((size_t)256*64*4);
  float* WHT0  = (float*)alloc((size_t)256*64*4);  // W_hh transposed for k_rec
  float* WHTf  = (float*)alloc((size_t)256*64*4);
  float* bs0   = (float*)alloc((size_t)256*4);
  float* bsf   = (float*)alloc((size_t)256*4);
  float* score = (float*)alloc((size_t)NN*4);
  float* dinv0 = (float*)alloc((size_t)NN*4);
  float* dinv1 = (float*)alloc((size_t)NN*4);
  unsigned long long* keys = (unsigned long long*)alloc((size_t)NN*8);
  int* degcnt  = (int*)alloc((size_t)NN*4);
  int* diagint = (int*)alloc((size_t)NN*4);
  int* ts      = (int*)alloc((size_t)NN*4);
  int* kp      = (int*)alloc((size_t)NN*4);
  int* mlist   = (int*)alloc((size_t)NN*4);
  int* minv    = (int*)alloc((size_t)NN*4);
  int* indptr  = (int*)alloc((size_t)(NN+1)*4);
  int* part    = (int*)alloc((size_t)NN*4);
  int* fillc   = (int*)alloc((size_t)NN*4);
  int* bsum    = (int*)alloc((size_t)256*4);
  int* csr_r   = (int*)alloc((size_t)EE*4);
  uint2* hash  = (uint2*)alloc((size_t)HASH_SIZE*8);
  unsigned* hist=(unsigned*)alloc((size_t)4*65536*4);
  unsigned* scal=(unsigned*)alloc(256);
  unsigned long long* selp = (unsigned long long*)(scal + 4);

  #define GRID1(n) dim3(((n)+255)/256), dim3(256), 0, stream
  #define GRIDW dim3((NN+3)/4), dim3(256), 0, stream

  // 1. merged init (hash, hist, per-node arrays, scalars, LSTM weight prep)
  k_init<<<GRID1(HASH_SIZE)>>>(hash, hist, degcnt, diagint, fillc, minv,
                               scal, selp, l0wih, l0bih, l0bhh, lfwih, lfbih, lfbhh,
                               l0whh, lfwhh, WT0, WTf, WHT0, WHTf, bs0, bsf);
  // 2. degcnt + hash build + mask detect + GCN0 matmul (merged)
  k_phase2<<<GRID1(NN*16)>>>(row, col, (const int*)mp, degcnt, hash, scal, x, W0, A);
  // 3-4. indptr prefix sum (+dinv0); psum3 self-computes block offsets
  k_psum1<<<dim3(PSB),dim3(256),0,stream>>>(degcnt, part, bsum, dinv0);
  k_psum3<<<dim3(PSB),dim3(256),0,stream>>>(part, bsum, indptr);
  // 5. csr fill + A^2 diag + mask compact
  k_phase4<<<GRID1(EE+NN)>>>(row, col, indptr, fillc, csr_r, hash, diagint, mp, scal, mlist, minv);

  // GCN0 gather (+ fused TopK score/key + radix round-0 hist)
  g_gcn0<<<GRIDW>>>(indptr, csr_r, dinv0, A, b0, pw, C, keys, score, hist);

  // TopK radix select (round-0 hist already done)
  k_pick<<<dim3(1),dim3(256),0,stream>>>(hist, selp, scal);
  for (int r2=1;r2<4;r2++){
    k_hist<<<GRID1(NN)>>>(keys, hist + r2*65536, selp, r2);
    k_pick<<<dim3(1),dim3(256),0,stream>>>(hist + r2*65536, selp, scal);
  }
  // pooled degree pass 1, then pass2+dinv1 merged with hp matmul
  k_tsg<<<GRID1(NN)>>>(indptr, csr_r, keys, selp, kp, ts);
  k_csgmm<<<GRID1(NN*16+NN)>>>(indptr, csr_r, ts, diagint, kp, dinv1, C, W1, score, Ebuf);
  g_t2<<<GRIDW>>>(indptr, csr_r, dinv1, Ebuf, A);

  // LSTM0 on x1 windows -> Hbuf (compact)
  k_xw<<<dim3(512),dim3(256),0,stream>>>(C, WT0, bs0, XW);
  k_rec<<<dim3(256),dim3(256),0,stream>>>(XW, WHT0, bs0, mlist, scal, Hbuf, 0);

  // y = res + up (fused: base select + relu(x2))
  g_agg2y<<<GRIDW>>>(indptr, csr_r, A, Ebuf, dinv1, diagint, kp, b1, C, Hbuf, minv, D);

  // up-GCN -> xo (B) and d_out
  k_mm64v<<<GRID1(NN*16)>>>(D, Wu, Ebuf);
  g_up<<<GRIDW>>>(indptr, csr_r, dinv0, Ebuf, bu, B, (float*)d_out);

  // final LSTM on xo windows, scatter into d_out masked rows
  k_xw<<<dim3(512),dim3(256),0,stream>>>(B, WTf, bsf, XW);
  k_rec<<<dim3(256),dim3(256),0,stream>>>(XW, WHTf, bsf, mlist, scal, (float*)d_out, 1);
  #undef GRIDW
  #undef GRID1
}

// Round 2
// 683.870 us; speedup vs baseline: 1.8286x; 1.8286x over previous
//
#include <hip/hip_runtime.h>
#include <math.h>

// Problem constants (fixed by reference setup)
#define NN 50000
#define EE 400000
#define CINV 32
#define KKEEP 25000          // ceil(0.5*N)
#define SEQL 5
#define HASH_BITS 20
#define HASH_SIZE (1u<<HASH_BITS)
#define HASH_MASK (HASH_SIZE-1u)
#define HEMPTY 0xFFFFFFFFu
#define PSB 196              // ceil(NN/256)

typedef float vf4 __attribute__((ext_vector_type(4)));

__device__ __forceinline__ float sigm(float x){ return __builtin_amdgcn_rcpf(1.f+__expf(-x)); }
__device__ __forceinline__ float ftanh(float x){ return 1.f - 2.f*__builtin_amdgcn_rcpf(1.f+__expf(2.f*x)); }

// ---------------- merged init (+ LSTM weight prep) ----------------
__global__ void k_init(uint2* __restrict__ hash, unsigned* __restrict__ hist,
                       int* __restrict__ degcnt, int* __restrict__ diagint,
                       int* __restrict__ fillc, int* __restrict__ minv,
                       unsigned* scal, unsigned long long* selp,
                       const float* __restrict__ w0, const float* __restrict__ b0i,
                       const float* __restrict__ b0h, const float* __restrict__ wf,
                       const float* __restrict__ bfi, const float* __restrict__ bfh,
                       float* __restrict__ WT0, float* __restrict__ WTf,
                       float* __restrict__ bs0, float* __restrict__ bsf){
  int i = blockIdx.x*256 + threadIdx.x;
  if (i < (int)HASH_SIZE) hash[i] = make_uint2(HEMPTY, 0u);
  if (i < 4*65536) hist[i] = 0u;
  if (i < NN){ degcnt[i]=0; diagint[i]=0; fillc[i]=0; minv[i]=-1; }
  if (i < 256*64){
    int g = i>>6, k = i&63;
    WT0[k*256+g] = w0[i];
    WTf[k*256+g] = wf[i];
  }
  if (i < 256){ bs0[i]=b0i[i]+b0h[i]; bsf[i]=bfi[i]+bfh[i]; }
  if (i == 0){ scal[0]=0u; scal[1]=0u; scal[3]=KKEEP; selp[0]=0ull; }
}

// ---------------- phase2: degcnt + hash build + mask detect + GCN0 matmul ----------------
// (edge work and the independent x@W0 matmul merged into one launch)
__global__ void k_phase2(const int* __restrict__ row, const int* __restrict__ col,
                         const int* __restrict__ mp, int* __restrict__ degcnt,
                         uint2* __restrict__ tab, unsigned* scal,
                         const float* __restrict__ X, const float* __restrict__ W,
                         float* __restrict__ Y){
  int idx = blockIdx.x*256 + threadIdx.x;
  if (idx < EE){
    int c = col[idx];
    atomicAdd(&degcnt[c], 1);
    unsigned key = (unsigned)row[idx]*50000u + (unsigned)c;
    unsigned h = (key*2654435761u) >> (32-HASH_BITS);
    for(;;){
      unsigned old = atomicCAS(&tab[h].x, HEMPTY, key);
      if (old==HEMPTY || old==key){ atomicAdd(&tab[h].y, 1u); break; }
      h = (h+1)&HASH_MASK;
    }
  }
  if (idx < NN/4){ if ((unsigned)mp[idx] > 1u) atomicOr(&scal[1], 1u); }
  if (idx < NN*16){
    int i = idx>>4, fq = idx&15;
    const vf4* X4 = (const vf4*)&X[i*CINV];
    const vf4* W4 = (const vf4*)W;
    vf4 acc = {0.f,0.f,0.f,0.f};
    #pragma unroll
    for (int kq=0;kq<CINV/4;kq++){
      vf4 xv = X4[kq];
      #pragma unroll
      for (int u=0;u<4;u++) acc += xv[u] * W4[(kq*4+u)*16+fq];
    }
    ((vf4*)Y)[i*16+fq] = acc;
  }
}

// ---------------- prefix sum (indptr) + dinv0 ----------------
__global__ void k_psum1(const int* __restrict__ deg, int* __restrict__ part,
                        int* __restrict__ bsum, float* __restrict__ dinv){
  __shared__ int sc[256];
  int b = blockIdx.x, t = threadIdx.x, i = b*256+t;
  int v = (i<NN) ? deg[i] : 0;
  if (i < NN) dinv[i] = rsqrtf((float)v + 2.0f);
  sc[t] = v; __syncthreads();
  for (int o=1;o<256;o<<=1){
    int x = (t>=o) ? sc[t-o] : 0;
    __syncthreads();
    sc[t] += x;
    __syncthreads();
  }
  if (i < NN) part[i] = sc[t]-v;
  if (t == 255) bsum[b] = sc[255];
}
// psum3 with per-block redundant scan of bsum (kills the separate psum2 launch)
__global__ void k_psum3(const int* __restrict__ part, const int* __restrict__ bsum,
                        int* __restrict__ indptr){
  __shared__ int sc[256];
  int t = threadIdx.x;
  int v = (t<PSB) ? bsum[t] : 0;
  sc[t] = v; __syncthreads();
  for (int o=1;o<256;o<<=1){
    int x = (t>=o) ? sc[t-o] : 0;
    __syncthreads();
    sc[t] += x;
    __syncthreads();
  }
  int bb = blockIdx.x;
  int ex = sc[bb] - ((bb<PSB) ? bsum[bb] : 0);   // exclusive prefix for this block
  int i = bb*256 + t;
  if (i < NN) indptr[i] = part[i] + ex;
  if (i == 0) indptr[NN] = EE;
}

// ---------------- csr fill + A^2 diag + mask compact ----------------
__global__ void k_phase4(const int* __restrict__ row, const int* __restrict__ col,
                         const int* __restrict__ indptr, int* __restrict__ fillc,
                         int* __restrict__ csr_r, const uint2* __restrict__ tab,
                         int* __restrict__ diagint, const void* __restrict__ mp,
                         unsigned* scal, int* __restrict__ mlist, int* __restrict__ minv){
  int idx = blockIdx.x*256 + threadIdx.x;
  if (idx < EE){
    int r = row[idx], c = col[idx];
    int pos = indptr[c] + atomicAdd(&fillc[c], 1);
    csr_r[pos] = r;
    unsigned rkey = (unsigned)c*50000u + (unsigned)r;
    unsigned h = (rkey*2654435761u) >> (32-HASH_BITS);
    for(;;){
      unsigned kk = tab[h].x;
      if (kk==rkey){ atomicAdd(&diagint[r], (int)tab[h].y); break; }
      if (kk==HEMPTY) break;
      h = (h+1)&HASH_MASK;
    }
  } else {
    int i = idx - EE;
    if (i < NN){
      int mv = scal[1] ? (int)((const unsigned char*)mp)[i] : ((const int*)mp)[i];
      if (mv){ int p = (int)atomicAdd(&scal[0], 1u); mlist[p] = i; minv[i] = p; }
    }
  }
}

// ---------------- remaining matmul (up-GCN input) ----------------
__global__ void k_mm64v(const float* __restrict__ X, const float* __restrict__ W, float* __restrict__ Y){
  int idx = blockIdx.x*256 + threadIdx.x;
  if (idx >= NN*16) return;
  int i = idx>>4, fq = idx&15;
  const vf4* X4 = (const vf4*)&X[i*64];
  const vf4* W4 = (const vf4*)W;
  vf4 acc = {0.f,0.f,0.f,0.f};
  #pragma unroll
  for (int kq=0;kq<16;kq++){
    vf4 xv = X4[kq];
    #pragma unroll
    for (int u=0;u<4;u++) acc += xv[u] * W4[(kq*4+u)*16+fq];
  }
  ((vf4*)Y)[i*16+fq] = acc;
}

// ---------------- CSR gather GCN kernels (wave per node, shuffle-pipelined) ----------------
__global__ void g_gcn0(const int* __restrict__ indptr, const int* __restrict__ csr_r,
                       const float* __restrict__ dinv, const float* __restrict__ H,
                       const float* __restrict__ b, const float* __restrict__ pw,
                       float* __restrict__ out, unsigned long long* __restrict__ keys,
                       float* __restrict__ score, unsigned* __restrict__ hist){
  int node = blockIdx.x*4 + (threadIdx.x>>6), lane = threadIdx.x&63;
  if (node >= NN) return;
  int s = __builtin_amdgcn_readfirstlane(indptr[node]);
  int e = __builtin_amdgcn_readfirstlane(indptr[node+1]);
  int deg = e - s;
  float a0=0.f,a1=0.f,a2=0.f,a3=0.f;
  for (int base=0; base<deg; base+=64){
    int take = min(64, deg-base);
    bool act = lane < take;
    int ii = act ? csr_r[s+base+lane] : 0;
    float dv = act ? dinv[ii] : 0.f;
    int j=0;
    for (; j+4<=take; j+=4){
      int r0=__shfl(ii,j,64), r1=__shfl(ii,j+1,64), r2=__shfl(ii,j+2,64), r3=__shfl(ii,j+3,64);
      float d0=__shfl(dv,j,64), d1=__shfl(dv,j+1,64), d2=__shfl(dv,j+2,64), d3=__shfl(dv,j+3,64);
      a0 += d0*H[(size_t)r0*64+lane];
      a1 += d1*H[(size_t)r1*64+lane];
      a2 += d2*H[(size_t)r2*64+lane];
      a3 += d3*H[(size_t)r3*64+lane];
    }
    for (; j<take; j++){
      int r0=__shfl(ii,j,64); float d0=__shfl(dv,j,64);
      a0 += d0*H[(size_t)r0*64+lane];
    }
  }
  float acc = (a0+a1)+(a2+a3);
  float di = dinv[node];
  float v = di*acc + 2.f*di*di*H[(size_t)node*64+lane] + b[lane];
  float x1v = fmaxf(v, 0.f);
  out[(size_t)node*64+lane] = x1v;
  // fused TopK score: s = tanh((x1 . pw)/||pw||)
  float pv = pw[lane];
  float nq = pv*pv;
  float dq = x1v*pv;
  for (int o=32;o;o>>=1){ nq += __shfl_down(nq, o, 64); dq += __shfl_down(dq, o, 64); }
  if (lane==0){
    float sv = tanhf(dq / sqrtf(nq));
    sv = sv + 0.0f;               // canonicalize -0 -> +0
    score[node] = sv;
    unsigned u = __float_as_uint(sv);
    unsigned asc = (u>>31) ? ~u : (u | 0x80000000u);
    unsigned desc = ~asc;
    keys[node] = (((unsigned long long)desc)<<32) | (unsigned)node;
    atomicAdd(&hist[desc>>16], 1u);      // radix round-0 histogram
  }
}
__global__ void g_t2(const int* __restrict__ indptr, const int* __restrict__ csr_r,
                     const float* __restrict__ dinv1, const float* __restrict__ hp,
                     float* __restrict__ t2){
  int node = blockIdx.x*4 + (threadIdx.x>>6), lane = threadIdx.x&63;
  if (node >= NN) return;
  int s = __builtin_amdgcn_readfirstlane(indptr[node]);
  int e = __builtin_amdgcn_readfirstlane(indptr[node+1]);
  int deg = e - s;
  float a0 = dinv1[node]*hp[(size_t)node*64+lane];   // self loop
  float a1 = 0.f;
  for (int base=0; base<deg; base+=64){
    int take = min(64, deg-base);
    bool act = lane < take;
    int ii = act ? csr_r[s+base+lane] : 0;
    float dv = act ? dinv1[ii] : 0.f;
    int j=0;
    for (; j+2<=take; j+=2){
      float d0=__shfl(dv,j,64), d1=__shfl(dv,j+1,64);
      int r0=__shfl(ii,j,64), r1=__shfl(ii,j+1,64);
      if (d0!=0.f) a0 += d0*hp[(size_t)r0*64+lane];
      if (d1!=0.f) a1 += d1*hp[(size_t)r1*64+lane];
    }
    for (; j<take; j++){
      float d0=__shfl(dv,j,64); int r0=__shfl(ii,j,64);
      if (d0!=0.f) a0 += d0*hp[(size_t)r0*64+lane];
    }
  }
  t2[(size_t)node*64+lane] = a0+a1;
}
// D[i] = (masked ? H0[minv[i]] : C[i]) + (kept ? relu(x2_i) : 0)
__global__ void g_agg2y(const int* __restrict__ indptr, const int* __restrict__ csr_r,
                        const float* __restrict__ t2, const float* __restrict__ hp,
                        const float* __restrict__ dinv1, const int* __restrict__ diagint,
                        const int* __restrict__ kp, const float* __restrict__ b1,
                        const float* __restrict__ C, const float* __restrict__ Hbuf,
                        const int* __restrict__ minv, float* __restrict__ D){
  int node = blockIdx.x*4 + (threadIdx.x>>6), lane = threadIdx.x&63;
  if (node >= NN) return;
  int mv = minv[node];
  float base = (mv >= 0) ? Hbuf[(size_t)mv*64+lane] : C[(size_t)node*64+lane];
  float add = 0.f;
  if (kp[node]){
    int s = __builtin_amdgcn_readfirstlane(indptr[node]);
    int e = __builtin_amdgcn_readfirstlane(indptr[node+1]);
    int deg = e - s;
    float a0 = t2[(size_t)node*64+lane];             // self loop
    float a1=0.f,a2=0.f,a3=0.f;
    for (int bs2=0; bs2<deg; bs2+=64){
      int take = min(64, deg-bs2);
      bool act = lane < take;
      int ii = act ? csr_r[s+bs2+lane] : 0;
      int j=0;
      for (; j+4<=take; j+=4){
        int r0=__shfl(ii,j,64), r1=__shfl(ii,j+1,64), r2=__shfl(ii,j+2,64), r3=__shfl(ii,j+3,64);
        a0 += t2[(size_t)r0*64+lane];
        a1 += t2[(size_t)r1*64+lane];
        a2 += t2[(size_t)r2*64+lane];
        a3 += t2[(size_t)r3*64+lane];
      }
      for (; j<take; j++){
        int r0=__shfl(ii,j,64);
        a0 += t2[(size_t)r0*64+lane];
      }
    }
    float acc = (a0+a1)+(a2+a3);
    float di = dinv1[node], hv = hp[(size_t)node*64+lane];
    float diag = (float)(diagint[node] + 1);
    float v = di*(acc - diag*di*hv) + 2.f*di*di*hv + b1[lane];
    add = fmaxf(v, 0.f);
  }
  D[(size_t)node*64+lane] = base + add;
}
__global__ void g_up(const int* __restrict__ indptr, const int* __restrict__ csr_r,
                     const float* __restrict__ dinv, const float* __restrict__ H,
                     const float* __restrict__ b, float* __restrict__ xo, float* __restrict__ out){
  int node = blockIdx.x*4 + (threadIdx.x>>6), lane = threadIdx.x&63;
  if (node >= NN) return;
  int s = __builtin_amdgcn_readfirstlane(indptr[node]);
  int e = __builtin_amdgcn_readfirstlane(indptr[node+1]);
  int deg = e - s;
  float a0=0.f,a1=0.f,a2=0.f,a3=0.f;
  for (int base=0; base<deg; base+=64){
    int take = min(64, deg-base);
    bool act = lane < take;
    int ii = act ? csr_r[s+base+lane] : 0;
    float dv = act ? dinv[ii] : 0.f;
    int j=0;
    for (; j+4<=take; j+=4){
      int r0=__shfl(ii,j,64), r1=__shfl(ii,j+1,64), r2=__shfl(ii,j+2,64), r3=__shfl(ii,j+3,64);
      float d0=__shfl(dv,j,64), d1=__shfl(dv,j+1,64), d2=__shfl(dv,j+2,64), d3=__shfl(dv,j+3,64);
      a0 += d0*H[(size_t)r0*64+lane];
      a1 += d1*H[(size_t)r1*64+lane];
      a2 += d2*H[(size_t)r2*64+lane];
      a3 += d3*H[(size_t)r3*64+lane];
    }
    for (; j<take; j++){
      int r0=__shfl(ii,j,64); float d0=__shfl(dv,j,64);
      a0 += d0*H[(size_t)r0*64+lane];
    }
  }
  float acc = (a0+a1)+(a2+a3);
  float di = dinv[node];
  float v = di*acc + 2.f*di*di*H[(size_t)node*64+lane] + b[lane];
  xo[(size_t)node*64+lane] = v; out[(size_t)node*64+lane] = v;
}

// ---------------- TopK radix select (round 0 hist fused into g_gcn0) ----------------
__global__ void k_hist(const unsigned long long* __restrict__ keys, unsigned* __restrict__ hist,
                       const unsigned long long* __restrict__ selp, int round){
  int i = blockIdx.x*256 + threadIdx.x;
  if (i >= NN) return;
  unsigned long long key = keys[i];
  int shift = 48 - 16*round;
  if ((key>>(shift+16)) == selp[0])
    atomicAdd(&hist[(unsigned)((key>>shift)&0xFFFFull)], 1u);
}
__global__ void k_pick(const unsigned* __restrict__ hist, unsigned long long* selp, unsigned* scal){
  __shared__ unsigned csum[256];
  __shared__ unsigned bins[256];
  __shared__ int schunk;
  int t = threadIdx.x;
  const uint4* h4 = (const uint4*)(hist + t*256);
  unsigned s = 0;
  #pragma unroll 8
  for (int j=0;j<64;j++){ uint4 v = h4[j]; s += v.x+v.y+v.z+v.w; }
  csum[t] = s;
  __syncthreads();
  if (t==0){
    unsigned rem = scal[3];
    int chunk = 255;
    for (int c2=0;c2<256;c2++){ unsigned cc=csum[c2]; if (rem>cc) rem-=cc; else { chunk=c2; break; } }
    schunk = chunk; scal[3] = rem;
  }
  __syncthreads();
  bins[t] = hist[schunk*256 + t];
  __syncthreads();
  if (t==0){
    unsigned rem = scal[3];
    int bin = schunk*256 + 255;
    for (int b=0;b<256;b++){ unsigned hv=bins[b]; if (rem>hv) rem-=hv; else { bin = schunk*256 + b; break; } }
    selp[0] = (selp[0]<<16) | (unsigned long long)(unsigned)bin;
    scal[3] = rem;
  }
}
// pooled degree pass 1 (CSR gather): kp[i]; ts[i] = sum_{r->i} kp[r] + kp[i]
__global__ void k_tsg(const int* __restrict__ indptr, const int* __restrict__ csr_r,
                      const unsigned long long* __restrict__ keys,
                      const unsigned long long* __restrict__ selp,
                      int* __restrict__ kp, int* __restrict__ ts){
  int i = blockIdx.x*256 + threadIdx.x;
  if (i >= NN) return;
  unsigned long long sp = selp[0];
  int s = indptr[i], e = indptr[i+1];
  int self = (keys[i] <= sp) ? 1 : 0;
  kp[i] = self;
  int acc = self;
  for (int j=s;j<e;j++) acc += (keys[csr_r[j]] <= sp) ? 1 : 0;
  ts[i] = acc;
}
// pooled degree pass 2 + dinv1 MERGED with hp = (x1*score)@W1 (both depend only on tsg)
__global__ void k_csgmm(const int* __restrict__ indptr, const int* __restrict__ csr_r,
                        const int* __restrict__ ts, const int* __restrict__ diagint,
                        const int* __restrict__ kp, float* __restrict__ dinv1,
                        const float* __restrict__ X, const float* __restrict__ W,
                        const float* __restrict__ sc, float* __restrict__ Y){
  int idx = blockIdx.x*256 + threadIdx.x;
  if (idx < NN*16){
    int i = idx>>4, fq = idx&15;
    if (!kp[i]) return;
    const vf4* X4 = (const vf4*)&X[i*64];
    const vf4* W4 = (const vf4*)W;
    vf4 acc = {0.f,0.f,0.f,0.f};
    #pragma unroll
    for (int kq=0;kq<16;kq++){
      vf4 xv = X4[kq];
      #pragma unroll
      for (int u=0;u<4;u++) acc += xv[u] * W4[(kq*4+u)*16+fq];
    }
    acc *= sc[i];
    ((vf4*)Y)[i*16+fq] = acc;
  } else {
    int i = idx - NN*16;
    if (i >= NN) return;
    int s = indptr[i], e = indptr[i+1];
    int acc = ts[i];
    for (int j=s;j<e;j++) acc += ts[csr_r[j]];
    dinv1[i] = kp[i] ? rsqrtf((float)(acc - diagint[i] - 1) + 2.0f) : 0.f;
  }
}

// ---------------- LSTM part 1: XW[n] = src[n] @ W_ih^T + (b_ih+b_hh) ----------------
__global__ __launch_bounds__(256) void k_xw(const float* __restrict__ src,
        const float* __restrict__ WT, const float* __restrict__ bsum,
        float* __restrict__ XW){
  __shared__ vf4 Wl[4096];              // 64 KB: WT[k][g] as vf4[(k*4+u)*64+fq]
  int t = threadIdx.x;
  const vf4* Wg = (const vf4*)WT;
  for (int u=t; u<4096; u+=256) Wl[u] = Wg[u];
  int fq = t & 63, wv = t >> 6;
  vf4 bias = ((const vf4*)bsum)[fq];
  __syncthreads();
  for (int g = blockIdx.x*4 + wv; g < NN/4; g += gridDim.x*4){
    int n0 = g*4;
    const vf4* X4 = (const vf4*)&src[(size_t)n0*64];   // 4 rows x 16 vf4
    vf4 a0=bias, a1=bias, a2=bias, a3=bias;
    #pragma unroll 4
    for (int kq=0;kq<16;kq++){
      vf4 x0 = X4[kq], x1 = X4[16+kq], x2 = X4[32+kq], x3 = X4[48+kq];
      vf4 w0 = Wl[(kq*4+0)*64+fq];
      vf4 w1 = Wl[(kq*4+1)*64+fq];
      vf4 w2 = Wl[(kq*4+2)*64+fq];
      vf4 w3 = Wl[(kq*4+3)*64+fq];
      a0 += x0.x*w0 + x0.y*w1 + x0.z*w2 + x0.w*w3;
      a1 += x1.x*w0 + x1.y*w1 + x1.z*w2 + x1.w*w3;
      a2 += x2.x*w0 + x2.y*w1 + x2.z*w2 + x2.w*w3;
      a3 += x3.x*w0 + x3.y*w1 + x3.z*w2 + x3.w*w3;
    }
    vf4* Y = (vf4*)XW;
    Y[(size_t)n0*64 + fq]       = a0;
    Y[(size_t)n0*64 + 64 + fq]  = a1;
    Y[(size_t)n0*64 + 128 + fq] = a2;
    Y[(size_t)n0*64 + 192 + fq] = a3;
  }
}

// ---------------- LSTM part 2: recurrence (hh-half only) ----------------
// R11: R7-proven cooperation (wave w holds gate-quadrant w rows, 16 vf4 =
// 64 regs, AGPR-demoted) but DOUBLE-PUMPED: 8 nodes/block in two sets A/B.
// Per timestep both matvecs (A then B, ~1100 cy of issue) run before the
// first barrier, and both nonlinear finishes run between the two barriers.
// Barriers per node-step halve; XW loads get a 2x-matvec of latency cover.
// Weights/lane unchanged vs R7 (this is NOT the regressed R9 8-node split).
__global__ __launch_bounds__(256) void k_rec(const float* __restrict__ XW,
        const float* __restrict__ whh, const float* __restrict__ bsum,
        const int* __restrict__ mlist, const unsigned* __restrict__ scal,
        float* __restrict__ dst, int scatter){
  int M = (int)scal[0];
  if (M < 0 || M > NN) M = 0;          // defensive (rocprof replay poisons scal)
  int w = threadIdx.x>>6, lane = threadIdx.x&63;
  int r = w*64 + lane;
  const vf4* g4 = (const vf4*)&whh[(size_t)r*64];
  vf4 wh[16];
  #pragma unroll
  for (int j=0;j<16;j++) wh[j] = g4[j];
  __shared__ __align__(16) float sh[8][64];
  __shared__ float gates[8][4][64];
  int ntask = (M+7)>>3;
  for (int task = blockIdx.x; task < ntask; task += gridDim.x){
    int mA = task*8 + w, mB = task*8 + 4 + w;
    bool vA = (mA < M), vB = (mB < M);
    int fb = (M>0) ? (M-1) : 0;
    int nodeA = mlist[vA ? mA : fb]; nodeA = min(max(nodeA, 0), NN-1);
    int nodeB = mlist[vB ? mB : fb]; nodeB = min(max(nodeB, 0), NN-1);
    float cA,hA,cB,hB;
    float xA0,xA1,xA2,xA3, xB0,xB1,xB2,xB3;
    {   // t = 0: h==0, gates = XW row (bias-only if left-padded)
      int rA = nodeA - (SEQL-1), rB = nodeB - (SEQL-1);
      if (rA >= 0){ const float* p=&XW[(size_t)rA*256]; xA0=p[lane];xA1=p[64+lane];xA2=p[128+lane];xA3=p[192+lane]; }
      else { xA0=bsum[lane];xA1=bsum[64+lane];xA2=bsum[128+lane];xA3=bsum[192+lane]; }
      if (rB >= 0){ const float* p=&XW[(size_t)rB*256]; xB0=p[lane];xB1=p[64+lane];xB2=p[128+lane];xB3=p[192+lane]; }
      else { xB0=bsum[lane];xB1=bsum[64+lane];xB2=bsum[128+lane];xB3=bsum[192+lane]; }
      cA = sigm(xA0)*ftanh(xA2); hA = sigm(xA3)*ftanh(cA);
      cB = sigm(xB0)*ftanh(xB2); hB = sigm(xB3)*ftanh(cB);
      sh[w][lane] = hA; sh[4+w][lane] = hB;
    }
    __syncthreads();
    for (int t=1;t<SEQL;t++){
      // prefetch this timestep's gate-x rows (consumed only after BOTH matvecs)
      int rA = nodeA - (SEQL-1) + t, rB = nodeB - (SEQL-1) + t;
      if (rA >= 0){ const float* p=&XW[(size_t)rA*256]; xA0=p[lane];xA1=p[64+lane];xA2=p[128+lane];xA3=p[192+lane]; }
      else { xA0=bsum[lane];xA1=bsum[64+lane];xA2=bsum[128+lane];xA3=bsum[192+lane]; }
      if (rB >= 0){ const float* p=&XW[(size_t)rB*256]; xB0=p[lane];xB1=p[64+lane];xB2=p[128+lane];xB3=p[192+lane]; }
      else { xB0=bsum[lane];xB1=bsum[64+lane];xB2=bsum[128+lane];xB3=bsum[192+lane]; }
      {   // matvec A: gate-quadrant w for nodes 0..3
        vf4 a0={0,0,0,0}, a1={0,0,0,0}, a2={0,0,0,0}, a3={0,0,0,0};
        #pragma unroll
        for (int j=0;j<16;j++){
          vf4 wj = wh[j];
          a0 += (*(const vf4*)&sh[0][j*4]) * wj;
          a1 += (*(const vf4*)&sh[1][j*4]) * wj;
          a2 += (*(const vf4*)&sh[2][j*4]) * wj;
          a3 += (*(const vf4*)&sh[3][j*4]) * wj;
        }
        gates[0][w][lane] = a0.x+a0.y+a0.z+a0.w;
        gates[1][w][lane] = a1.x+a1.y+a1.z+a1.w;
        gates[2][w][lane] = a2.x+a2.y+a2.z+a2.w;
        gates[3][w][lane] = a3.x+a3.y+a3.z+a3.w;
      }
      {   // matvec B: gate-quadrant w for nodes 4..7
        vf4 a0={0,0,0,0}, a1={0,0,0,0}, a2={0,0,0,0}, a3={0,0,0,0};
        #pragma unroll
        for (int j=0;j<16;j++){
          vf4 wj = wh[j];
          a0 += (*(const vf4*)&sh[4][j*4]) * wj;
          a1 += (*(const vf4*)&sh[5][j*4]) * wj;
          a2 += (*(const vf4*)&sh[6][j*4]) * wj;
          a3 += (*(const vf4*)&sh[7][j*4]) * wj;
        }
        gates[4][w][lane] = a0.x+a0.y+a0.z+a0.w;
        gates[5][w][lane] = a1.x+a1.y+a1.z+a1.w;
        gates[6][w][lane] = a2.x+a2.y+a2.z+a2.w;
        gates[7][w][lane] = a3.x+a3.y+a3.z+a3.w;
      }
      __syncthreads();
      // finish A (wave w owns node w)
      float gi = gates[w][0][lane] + xA0;
      float gf = gates[w][1][lane] + xA1;
      float gg = gates[w][2][lane] + xA2;
      float go = gates[w][3][lane] + xA3;
      cA = sigm(gf)*cA + sigm(gi)*ftanh(gg);
      hA = sigm(go)*ftanh(cA);
      sh[w][lane] = hA;
      // finish B (wave w owns node 4+w)
      float hi = gates[4+w][0][lane] + xB0;
      float hf = gates[4+w][1][lane] + xB1;
      float hg = gates[4+w][2][lane] + xB2;
      float ho = gates[4+w][3][lane] + xB3;
      cB = sigm(hf)*cB + sigm(hi)*ftanh(hg);
      hB = sigm(ho)*ftanh(cB);
      sh[4+w][lane] = hB;
      __syncthreads();
    }
    if (vA){ size_t o = scatter ? ((size_t)nodeA*64 + lane) : ((size_t)mA*64 + lane); dst[o] = hA; }
    if (vB){ size_t o = scatter ? ((size_t)nodeB*64 + lane) : ((size_t)mB*64 + lane); dst[o] = hB; }
  }
}

// ==========================================================================
extern "C" void kernel_launch(void* const* d_in, const int* in_sizes, int n_in,
                              void* d_out, int out_size, void* d_ws, size_t ws_size,
                              hipStream_t stream) {
  const float* x   = (const float*)d_in[0];
  const int*   ei  = (const int*)d_in[1];
  const int*   row = ei;
  const int*   col = ei + EE;
  const void*  mp  = d_in[2];
  const float* W0  = (const float*)d_in[3];
  const float* b0  = (const float*)d_in[4];
  const float* W1  = (const float*)d_in[5];
  const float* b1  = (const float*)d_in[6];
  const float* pw  = (const float*)d_in[7];
  const float* Wu  = (const float*)d_in[8];
  const float* bu  = (const float*)d_in[9];
  const float* l0wih=(const float*)d_in[10];
  const float* l0whh=(const float*)d_in[11];
  const float* l0bih=(const float*)d_in[12];
  const float* l0bhh=(const float*)d_in[13];
  const float* lfwih=(const float*)d_in[14];
  const float* lfwhh=(const float*)d_in[15];
  const float* lfbih=(const float*)d_in[16];
  const float* lfbhh=(const float*)d_in[17];

  char* wp = (char*)d_ws;
  auto alloc = [&](size_t bytes)->char*{ char* p = wp; wp += ((bytes+255)/256)*256; return p; };
  float* A     = (float*)alloc((size_t)NN*64*4);   // h0 -> t2
  float* B     = (float*)alloc((size_t)NN*64*4);   // xo
  float* C     = (float*)alloc((size_t)NN*64*4);   // x1
  float* D     = (float*)alloc((size_t)NN*64*4);   // y
  float* Ebuf  = (float*)alloc((size_t)NN*64*4);   // hp -> up-GCN input
  float* Hbuf  = (float*)alloc((size_t)NN*64*4);   // LSTM0 compact output
  float* XW    = (float*)alloc((size_t)NN*256*4);  // gate-x precompute (51.2 MB)
  float* WT0   = (float*)alloc((size_t)256*64*4);
  float* WTf   = (float*)alloc((size_t)256*64*4);
  float* bs0   = (float*)alloc((size_t)256*4);
  float* bsf   = (float*)alloc((size_t)256*4);
  float* score = (float*)alloc((size_t)NN*4);
  float* dinv0 = (float*)alloc((size_t)NN*4);
  float* dinv1 = (float*)alloc((size_t)NN*4);
  unsigned long long* keys = (unsigned long long*)alloc((size_t)NN*8);
  int* degcnt  = (int*)alloc((size_t)NN*4);
  int* diagint = (int*)alloc((size_t)NN*4);
  int* ts      = (int*)alloc((size_t)NN*4);
  int* kp      = (int*)alloc((size_t)NN*4);
  int* mlist   = (int*)alloc((size_t)NN*4);
  int* minv    = (int*)alloc((size_t)NN*4);
  int* indptr  = (int*)alloc((size_t)(NN+1)*4);
  int* part    = (int*)alloc((size_t)NN*4);
  int* fillc   = (int*)alloc((size_t)NN*4);
  int* bsum    = (int*)alloc((size_t)256*4);
  int* csr_r   = (int*)alloc((size_t)EE*4);
  uint2* hash  = (uint2*)alloc((size_t)HASH_SIZE*8);
  unsigned* hist=(unsigned*)alloc((size_t)4*65536*4);
  unsigned* scal=(unsigned*)alloc(256);
  unsigned long long* selp = (unsigned long long*)(scal + 4);

  #define GRID1(n) dim3(((n)+255)/256), dim3(256), 0, stream
  #define GRIDW dim3((NN+3)/4), dim3(256), 0, stream

  // 1. merged init (hash, hist, per-node arrays, scalars, LSTM weight prep)
  k_init<<<GRID1(HASH_SIZE)>>>(hash, hist, degcnt, diagint, fillc, minv,
                               scal, selp, l0wih, l0bih, l0bhh, lfwih, lfbih, lfbhh,
                               WT0, WTf, bs0, bsf);
  // 2. degcnt + hash build + mask detect + GCN0 matmul (merged)
  k_phase2<<<GRID1(NN*16)>>>(row, col, (const int*)mp, degcnt, hash, scal, x, W0, A);
  // 3-4. indptr prefix sum (+dinv0); psum3 self-computes block offsets
  k_psum1<<<dim3(PSB),dim3(256),0,stream>>>(degcnt, part, bsum, dinv0);
  k_psum3<<<dim3(PSB),dim3(256),0,stream>>>(part, bsum, indptr);
  // 5. csr fill + A^2 diag + mask compact
  k_phase4<<<GRID1(EE+NN)>>>(row, col, indptr, fillc, csr_r, hash, diagint, mp, scal, mlist, minv);

  // GCN0 gather (+ fused TopK score/key + radix round-0 hist)
  g_gcn0<<<GRIDW>>>(indptr, csr_r, dinv0, A, b0, pw, C, keys, score, hist);

  // TopK radix select (round-0 hist already done)
  k_pick<<<dim3(1),dim3(256),0,stream>>>(hist, selp, scal);
  for (int r2=1;r2<4;r2++){
    k_hist<<<GRID1(NN)>>>(keys, hist + r2*65536, selp, r2);
    k_pick<<<dim3(1),dim3(256),0,stream>>>(hist + r2*65536, selp, scal);
  }
  // pooled degree pass 1, then pass2+dinv1 merged with hp matmul
  k_tsg<<<GRID1(NN)>>>(indptr, csr_r, keys, selp, kp, ts);
  k_csgmm<<<GRID1(NN*16+NN)>>>(indptr, csr_r, ts, diagint, kp, dinv1, C, W1, score, Ebuf);
  g_t2<<<GRIDW>>>(indptr, csr_r, dinv1, Ebuf, A);

  // LSTM0 on x1 windows -> Hbuf (compact)
  k_xw<<<dim3(512),dim3(256),0,stream>>>(C, WT0, bs0, XW);
  k_rec<<<dim3(1024),dim3(256),0,stream>>>(XW, l0whh, bs0, mlist, scal, Hbuf, 0);

  // y = res + up (fused: base select + relu(x2))
  g_agg2y<<<GRIDW>>>(indptr, csr_r, A, Ebuf, dinv1, diagint, kp, b1, C, Hbuf, minv, D);

  // up-GCN -> xo (B) and d_out
  k_mm64v<<<GRID1(NN*16)>>>(D, Wu, Ebuf);
  g_up<<<GRIDW>>>(indptr, csr_r, dinv0, Ebuf, bu, B, (float*)d_out);

  // final LSTM on xo windows, scatter into d_out masked rows
  k_xw<<<dim3(512),dim3(256),0,stream>>>(B, WTf, bsf, XW);
  k_rec<<<dim3(1024),dim3(256),0,stream>>>(XW, lfwhh, bsf, mlist, scal, (float*)d_out, 1);
  #undef GRIDW
  #undef GRID1
}

// Round 3
// 648.459 us; speedup vs baseline: 1.9284x; 1.0546x over previous
//
#include <hip/hip_runtime.h>
#include <math.h>

// Problem constants (fixed by reference setup)
#define NN 50000
#define EE 400000
#define CINV 32
#define KKEEP 25000          // ceil(0.5*N)
#define SEQL 5
#define HASH_BITS 20
#define HASH_SIZE (1u<<HASH_BITS)
#define HASH_MASK (HASH_SIZE-1u)
#define HEMPTY 0xFFFFFFFFu
#define PSB 196              // ceil(NN/256)

typedef float vf4 __attribute__((ext_vector_type(4)));

__device__ __forceinline__ float sigm(float x){ return __builtin_amdgcn_rcpf(1.f+__expf(-x)); }
__device__ __forceinline__ float ftanh(float x){ return 1.f - 2.f*__builtin_amdgcn_rcpf(1.f+__expf(2.f*x)); }

// ---------------- merged init (+ LSTM weight prep) ----------------
// R12: WT/bsum are PERMUTED so k_xw emits XW in interleaved layout
// XW[n][ch*4+g] = gate g (i,f,g,o) of channel ch  ->  k_rec reads ONE
// dwordx4 per node-step instead of 4 strided dwords.
__global__ void k_init(uint2* __restrict__ hash, unsigned* __restrict__ hist,
                       int* __restrict__ degcnt, int* __restrict__ diagint,
                       int* __restrict__ fillc, int* __restrict__ minv,
                       unsigned* scal, unsigned long long* selp,
                       const float* __restrict__ w0, const float* __restrict__ b0i,
                       const float* __restrict__ b0h, const float* __restrict__ wf,
                       const float* __restrict__ bfi, const float* __restrict__ bfh,
                       float* __restrict__ WT0, float* __restrict__ WTf,
                       float* __restrict__ bs0, float* __restrict__ bsf){
  int i = blockIdx.x*256 + threadIdx.x;
  if (i < (int)HASH_SIZE) hash[i] = make_uint2(HEMPTY, 0u);
  if (i < 4*65536) hist[i] = 0u;
  if (i < NN){ degcnt[i]=0; diagint[i]=0; fillc[i]=0; minv[i]=-1; }
  if (i < 256*64){
    int r = i>>6, k = i&63;
    int dst = k*256 + (r&63)*4 + (r>>6);   // [k][ch][gate]
    WT0[dst] = w0[i];
    WTf[dst] = wf[i];
  }
  if (i < 256){
    int dst = (i&63)*4 + (i>>6);           // [ch][gate]
    bs0[dst]=b0i[i]+b0h[i]; bsf[dst]=bfi[i]+bfh[i];
  }
  if (i == 0){ scal[0]=0u; scal[1]=0u; scal[3]=KKEEP; selp[0]=0ull; }
}

// ---------------- phase2: degcnt + hash build + mask detect + GCN0 matmul ----------------
// (edge work and the independent x@W0 matmul merged into one launch)
__global__ void k_phase2(const int* __restrict__ row, const int* __restrict__ col,
                         const int* __restrict__ mp, int* __restrict__ degcnt,
                         uint2* __restrict__ tab, unsigned* scal,
                         const float* __restrict__ X, const float* __restrict__ W,
                         float* __restrict__ Y){
  int idx = blockIdx.x*256 + threadIdx.x;
  if (idx < EE){
    int c = col[idx];
    atomicAdd(&degcnt[c], 1);
    unsigned key = (unsigned)row[idx]*50000u + (unsigned)c;
    unsigned h = (key*2654435761u) >> (32-HASH_BITS);
    for(;;){
      unsigned old = atomicCAS(&tab[h].x, HEMPTY, key);
      if (old==HEMPTY || old==key){ atomicAdd(&tab[h].y, 1u); break; }
      h = (h+1)&HASH_MASK;
    }
  }
  if (idx < NN/4){ if ((unsigned)mp[idx] > 1u) atomicOr(&scal[1], 1u); }
  if (idx < NN*16){
    int i = idx>>4, fq = idx&15;
    const vf4* X4 = (const vf4*)&X[i*CINV];
    const vf4* W4 = (const vf4*)W;
    vf4 acc = {0.f,0.f,0.f,0.f};
    #pragma unroll
    for (int kq=0;kq<CINV/4;kq++){
      vf4 xv = X4[kq];
      #pragma unroll
      for (int u=0;u<4;u++) acc += xv[u] * W4[(kq*4+u)*16+fq];
    }
    ((vf4*)Y)[i*16+fq] = acc;
  }
}

// ---------------- prefix sum (indptr) + dinv0 ----------------
__global__ void k_psum1(const int* __restrict__ deg, int* __restrict__ part,
                        int* __restrict__ bsum, float* __restrict__ dinv){
  __shared__ int sc[256];
  int b = blockIdx.x, t = threadIdx.x, i = b*256+t;
  int v = (i<NN) ? deg[i] : 0;
  if (i < NN) dinv[i] = rsqrtf((float)v + 2.0f);
  sc[t] = v; __syncthreads();
  for (int o=1;o<256;o<<=1){
    int x = (t>=o) ? sc[t-o] : 0;
    __syncthreads();
    sc[t] += x;
    __syncthreads();
  }
  if (i < NN) part[i] = sc[t]-v;
  if (t == 255) bsum[b] = sc[255];
}
// psum3 with per-block redundant scan of bsum (kills the separate psum2 launch)
__global__ void k_psum3(const int* __restrict__ part, const int* __restrict__ bsum,
                        int* __restrict__ indptr){
  __shared__ int sc[256];
  int t = threadIdx.x;
  int v = (t<PSB) ? bsum[t] : 0;
  sc[t] = v; __syncthreads();
  for (int o=1;o<256;o<<=1){
    int x = (t>=o) ? sc[t-o] : 0;
    __syncthreads();
    sc[t] += x;
    __syncthreads();
  }
  int bb = blockIdx.x;
  int ex = sc[bb] - ((bb<PSB) ? bsum[bb] : 0);   // exclusive prefix for this block
  int i = bb*256 + t;
  if (i < NN) indptr[i] = part[i] + ex;
  if (i == 0) indptr[NN] = EE;
}

// ---------------- csr fill + A^2 diag + mask compact ----------------
__global__ void k_phase4(const int* __restrict__ row, const int* __restrict__ col,
                         const int* __restrict__ indptr, int* __restrict__ fillc,
                         int* __restrict__ csr_r, const uint2* __restrict__ tab,
                         int* __restrict__ diagint, const void* __restrict__ mp,
                         unsigned* scal, int* __restrict__ mlist, int* __restrict__ minv){
  int idx = blockIdx.x*256 + threadIdx.x;
  if (idx < EE){
    int r = row[idx], c = col[idx];
    int pos = indptr[c] + atomicAdd(&fillc[c], 1);
    csr_r[pos] = r;
    unsigned rkey = (unsigned)c*50000u + (unsigned)r;
    unsigned h = (rkey*2654435761u) >> (32-HASH_BITS);
    for(;;){
      unsigned kk = tab[h].x;
      if (kk==rkey){ atomicAdd(&diagint[r], (int)tab[h].y); break; }
      if (kk==HEMPTY) break;
      h = (h+1)&HASH_MASK;
    }
  } else {
    int i = idx - EE;
    if (i < NN){
      int mv = scal[1] ? (int)((const unsigned char*)mp)[i] : ((const int*)mp)[i];
      if (mv){ int p = (int)atomicAdd(&scal[0], 1u); mlist[p] = i; minv[i] = p; }
    }
  }
}

// ---------------- remaining matmul (up-GCN input) ----------------
__global__ void k_mm64v(const float* __restrict__ X, const float* __restrict__ W, float* __restrict__ Y){
  int idx = blockIdx.x*256 + threadIdx.x;
  if (idx >= NN*16) return;
  int i = idx>>4, fq = idx&15;
  const vf4* X4 = (const vf4*)&X[i*64];
  const vf4* W4 = (const vf4*)W;
  vf4 acc = {0.f,0.f,0.f,0.f};
  #pragma unroll
  for (int kq=0;kq<16;kq++){
    vf4 xv = X4[kq];
    #pragma unroll
    for (int u=0;u<4;u++) acc += xv[u] * W4[(kq*4+u)*16+fq];
  }
  ((vf4*)Y)[i*16+fq] = acc;
}

// ---------------- CSR gather GCN kernels (wave per node, shuffle-pipelined) ----------------
__global__ void g_gcn0(const int* __restrict__ indptr, const int* __restrict__ csr_r,
                       const float* __restrict__ dinv, const float* __restrict__ H,
                       const float* __restrict__ b, const float* __restrict__ pw,
                       float* __restrict__ out, unsigned long long* __restrict__ keys,
                       float* __restrict__ score, unsigned* __restrict__ hist){
  int node = blockIdx.x*4 + (threadIdx.x>>6), lane = threadIdx.x&63;
  if (node >= NN) return;
  int s = __builtin_amdgcn_readfirstlane(indptr[node]);
  int e = __builtin_amdgcn_readfirstlane(indptr[node+1]);
  int deg = e - s;
  float a0=0.f,a1=0.f,a2=0.f,a3=0.f;
  for (int base=0; base<deg; base+=64){
    int take = min(64, deg-base);
    bool act = lane < take;
    int ii = act ? csr_r[s+base+lane] : 0;
    float dv = act ? dinv[ii] : 0.f;
    int j=0;
    for (; j+4<=take; j+=4){
      int r0=__shfl(ii,j,64), r1=__shfl(ii,j+1,64), r2=__shfl(ii,j+2,64), r3=__shfl(ii,j+3,64);
      float d0=__shfl(dv,j,64), d1=__shfl(dv,j+1,64), d2=__shfl(dv,j+2,64), d3=__shfl(dv,j+3,64);
      a0 += d0*H[(size_t)r0*64+lane];
      a1 += d1*H[(size_t)r1*64+lane];
      a2 += d2*H[(size_t)r2*64+lane];
      a3 += d3*H[(size_t)r3*64+lane];
    }
    for (; j<take; j++){
      int r0=__shfl(ii,j,64); float d0=__shfl(dv,j,64);
      a0 += d0*H[(size_t)r0*64+lane];
    }
  }
  float acc = (a0+a1)+(a2+a3);
  float di = dinv[node];
  float v = di*acc + 2.f*di*di*H[(size_t)node*64+lane] + b[lane];
  float x1v = fmaxf(v, 0.f);
  out[(size_t)node*64+lane] = x1v;
  // fused TopK score: s = tanh((x1 . pw)/||pw||)
  float pv = pw[lane];
  float nq = pv*pv;
  float dq = x1v*pv;
  for (int o=32;o;o>>=1){ nq += __shfl_down(nq, o, 64); dq += __shfl_down(dq, o, 64); }
  if (lane==0){
    float sv = tanhf(dq / sqrtf(nq));
    sv = sv + 0.0f;               // canonicalize -0 -> +0
    score[node] = sv;
    unsigned u = __float_as_uint(sv);
    unsigned asc = (u>>31) ? ~u : (u | 0x80000000u);
    unsigned desc = ~asc;
    keys[node] = (((unsigned long long)desc)<<32) | (unsigned)node;
    atomicAdd(&hist[desc>>16], 1u);      // radix round-0 histogram
  }
}
__global__ void g_t2(const int* __restrict__ indptr, const int* __restrict__ csr_r,
                     const float* __restrict__ dinv1, const float* __restrict__ hp,
                     float* __restrict__ t2){
  int node = blockIdx.x*4 + (threadIdx.x>>6), lane = threadIdx.x&63;
  if (node >= NN) return;
  int s = __builtin_amdgcn_readfirstlane(indptr[node]);
  int e = __builtin_amdgcn_readfirstlane(indptr[node+1]);
  int deg = e - s;
  float a0 = dinv1[node]*hp[(size_t)node*64+lane];   // self loop
  float a1 = 0.f;
  for (int base=0; base<deg; base+=64){
    int take = min(64, deg-base);
    bool act = lane < take;
    int ii = act ? csr_r[s+base+lane] : 0;
    float dv = act ? dinv1[ii] : 0.f;
    int j=0;
    for (; j+2<=take; j+=2){
      float d0=__shfl(dv,j,64), d1=__shfl(dv,j+1,64);
      int r0=__shfl(ii,j,64), r1=__shfl(ii,j+1,64);
      if (d0!=0.f) a0 += d0*hp[(size_t)r0*64+lane];
      if (d1!=0.f) a1 += d1*hp[(size_t)r1*64+lane];
    }
    for (; j<take; j++){
      float d0=__shfl(dv,j,64); int r0=__shfl(ii,j,64);
      if (d0!=0.f) a0 += d0*hp[(size_t)r0*64+lane];
    }
  }
  t2[(size_t)node*64+lane] = a0+a1;
}
// D[i] = (masked ? H0[minv[i]] : C[i]) + (kept ? relu(x2_i) : 0)
__global__ void g_agg2y(const int* __restrict__ indptr, const int* __restrict__ csr_r,
                        const float* __restrict__ t2, const float* __restrict__ hp,
                        const float* __restrict__ dinv1, const int* __restrict__ diagint,
                        const int* __restrict__ kp, const float* __restrict__ b1,
                        const float* __restrict__ C, const float* __restrict__ Hbuf,
                        const int* __restrict__ minv, float* __restrict__ D){
  int node = blockIdx.x*4 + (threadIdx.x>>6), lane = threadIdx.x&63;
  if (node >= NN) return;
  int mv = minv[node];
  float base = (mv >= 0) ? Hbuf[(size_t)mv*64+lane] : C[(size_t)node*64+lane];
  float add = 0.f;
  if (kp[node]){
    int s = __builtin_amdgcn_readfirstlane(indptr[node]);
    int e = __builtin_amdgcn_readfirstlane(indptr[node+1]);
    int deg = e - s;
    float a0 = t2[(size_t)node*64+lane];             // self loop
    float a1=0.f,a2=0.f,a3=0.f;
    for (int bs2=0; bs2<deg; bs2+=64){
      int take = min(64, deg-bs2);
      bool act = lane < take;
      int ii = act ? csr_r[s+bs2+lane] : 0;
      int j=0;
      for (; j+4<=take; j+=4){
        int r0=__shfl(ii,j,64), r1=__shfl(ii,j+1,64), r2=__shfl(ii,j+2,64), r3=__shfl(ii,j+3,64);
        a0 += t2[(size_t)r0*64+lane];
        a1 += t2[(size_t)r1*64+lane];
        a2 += t2[(size_t)r2*64+lane];
        a3 += t2[(size_t)r3*64+lane];
      }
      for (; j<take; j++){
        int r0=__shfl(ii,j,64);
        a0 += t2[(size_t)r0*64+lane];
      }
    }
    float acc = (a0+a1)+(a2+a3);
    float di = dinv1[node], hv = hp[(size_t)node*64+lane];
    float diag = (float)(diagint[node] + 1);
    float v = di*(acc - diag*di*hv) + 2.f*di*di*hv + b1[lane];
    add = fmaxf(v, 0.f);
  }
  D[(size_t)node*64+lane] = base + add;
}
__global__ void g_up(const int* __restrict__ indptr, const int* __restrict__ csr_r,
                     const float* __restrict__ dinv, const float* __restrict__ H,
                     const float* __restrict__ b, float* __restrict__ xo, float* __restrict__ out){
  int node = blockIdx.x*4 + (threadIdx.x>>6), lane = threadIdx.x&63;
  if (node >= NN) return;
  int s = __builtin_amdgcn_readfirstlane(indptr[node]);
  int e = __builtin_amdgcn_readfirstlane(indptr[node+1]);
  int deg = e - s;
  float a0=0.f,a1=0.f,a2=0.f,a3=0.f;
  for (int base=0; base<deg; base+=64){
    int take = min(64, deg-base);
    bool act = lane < take;
    int ii = act ? csr_r[s+base+lane] : 0;
    float dv = act ? dinv[ii] : 0.f;
    int j=0;
    for (; j+4<=take; j+=4){
      int r0=__shfl(ii,j,64), r1=__shfl(ii,j+1,64), r2=__shfl(ii,j+2,64), r3=__shfl(ii,j+3,64);
      float d0=__shfl(dv,j,64), d1=__shfl(dv,j+1,64), d2=__shfl(dv,j+2,64), d3=__shfl(dv,j+3,64);
      a0 += d0*H[(size_t)r0*64+lane];
      a1 += d1*H[(size_t)r1*64+lane];
      a2 += d2*H[(size_t)r2*64+lane];
      a3 += d3*H[(size_t)r3*64+lane];
    }
    for (; j<take; j++){
      int r0=__shfl(ii,j,64); float d0=__shfl(dv,j,64);
      a0 += d0*H[(size_t)r0*64+lane];
    }
  }
  float acc = (a0+a1)+(a2+a3);
  float di = dinv[node];
  float v = di*acc + 2.f*di*di*H[(size_t)node*64+lane] + b[lane];
  xo[(size_t)node*64+lane] = v; out[(size_t)node*64+lane] = v;
}

// ---------------- TopK radix select (round 0 hist fused into g_gcn0) ----------------
__global__ void k_hist(const unsigned long long* __restrict__ keys, unsigned* __restrict__ hist,
                       const unsigned long long* __restrict__ selp, int round){
  int i = blockIdx.x*256 + threadIdx.x;
  if (i >= NN) return;
  unsigned long long key = keys[i];
  int shift = 48 - 16*round;
  if ((key>>(shift+16)) == selp[0])
    atomicAdd(&hist[(unsigned)((key>>shift)&0xFFFFull)], 1u);
}
__global__ void k_pick(const unsigned* __restrict__ hist, unsigned long long* selp, unsigned* scal){
  __shared__ unsigned csum[256];
  __shared__ unsigned bins[256];
  __shared__ int schunk;
  int t = threadIdx.x;
  const uint4* h4 = (const uint4*)(hist + t*256);
  unsigned s = 0;
  #pragma unroll 8
  for (int j=0;j<64;j++){ uint4 v = h4[j]; s += v.x+v.y+v.z+v.w; }
  csum[t] = s;
  __syncthreads();
  if (t==0){
    unsigned rem = scal[3];
    int chunk = 255;
    for (int c2=0;c2<256;c2++){ unsigned cc=csum[c2]; if (rem>cc) rem-=cc; else { chunk=c2; break; } }
    schunk = chunk; scal[3] = rem;
  }
  __syncthreads();
  bins[t] = hist[schunk*256 + t];
  __syncthreads();
  if (t==0){
    unsigned rem = scal[3];
    int bin = schunk*256 + 255;
    for (int b=0;b<256;b++){ unsigned hv=bins[b]; if (rem>hv) rem-=hv; else { bin = schunk*256 + b; break; } }
    selp[0] = (selp[0]<<16) | (unsigned long long)(unsigned)bin;
    scal[3] = rem;
  }
}
// pooled degree pass 1 (CSR gather): kp[i]; ts[i] = sum_{r->i} kp[r] + kp[i]
__global__ void k_tsg(const int* __restrict__ indptr, const int* __restrict__ csr_r,
                      const unsigned long long* __restrict__ keys,
                      const unsigned long long* __restrict__ selp,
                      int* __restrict__ kp, int* __restrict__ ts){
  int i = blockIdx.x*256 + threadIdx.x;
  if (i >= NN) return;
  unsigned long long sp = selp[0];
  int s = indptr[i], e = indptr[i+1];
  int self = (keys[i] <= sp) ? 1 : 0;
  kp[i] = self;
  int acc = self;
  for (int j=s;j<e;j++) acc += (keys[csr_r[j]] <= sp) ? 1 : 0;
  ts[i] = acc;
}
// pooled degree pass 2 + dinv1 MERGED with hp = (x1*score)@W1 (both depend only on tsg)
__global__ void k_csgmm(const int* __restrict__ indptr, const int* __restrict__ csr_r,
                        const int* __restrict__ ts, const int* __restrict__ diagint,
                        const int* __restrict__ kp, float* __restrict__ dinv1,
                        const float* __restrict__ X, const float* __restrict__ W,
                        const float* __restrict__ sc, float* __restrict__ Y){
  int idx = blockIdx.x*256 + threadIdx.x;
  if (idx < NN*16){
    int i = idx>>4, fq = idx&15;
    if (!kp[i]) return;
    const vf4* X4 = (const vf4*)&X[i*64];
    const vf4* W4 = (const vf4*)W;
    vf4 acc = {0.f,0.f,0.f,0.f};
    #pragma unroll
    for (int kq=0;kq<16;kq++){
      vf4 xv = X4[kq];
      #pragma unroll
      for (int u=0;u<4;u++) acc += xv[u] * W4[(kq*4+u)*16+fq];
    }
    acc *= sc[i];
    ((vf4*)Y)[i*16+fq] = acc;
  } else {
    int i = idx - NN*16;
    if (i >= NN) return;
    int s = indptr[i], e = indptr[i+1];
    int acc = ts[i];
    for (int j=s;j<e;j++) acc += ts[csr_r[j]];
    dinv1[i] = kp[i] ? rsqrtf((float)(acc - diagint[i] - 1) + 2.0f) : 0.f;
  }
}

// ---------------- LSTM part 1: XW[n] = src[n] @ W_ih^T + (b_ih+b_hh) ----------------
// (unchanged code; WT/bsum permutation in k_init makes the output layout
//  interleaved: XW[n][ch*4+g])
__global__ __launch_bounds__(256) void k_xw(const float* __restrict__ src,
        const float* __restrict__ WT, const float* __restrict__ bsum,
        float* __restrict__ XW){
  __shared__ vf4 Wl[4096];              // 64 KB
  int t = threadIdx.x;
  const vf4* Wg = (const vf4*)WT;
  for (int u=t; u<4096; u+=256) Wl[u] = Wg[u];
  int fq = t & 63, wv = t >> 6;
  vf4 bias = ((const vf4*)bsum)[fq];
  __syncthreads();
  for (int g = blockIdx.x*4 + wv; g < NN/4; g += gridDim.x*4){
    int n0 = g*4;
    const vf4* X4 = (const vf4*)&src[(size_t)n0*64];   // 4 rows x 16 vf4
    vf4 a0=bias, a1=bias, a2=bias, a3=bias;
    #pragma unroll 4
    for (int kq=0;kq<16;kq++){
      vf4 x0 = X4[kq], x1 = X4[16+kq], x2 = X4[32+kq], x3 = X4[48+kq];
      vf4 w0 = Wl[(kq*4+0)*64+fq];
      vf4 w1 = Wl[(kq*4+1)*64+fq];
      vf4 w2 = Wl[(kq*4+2)*64+fq];
      vf4 w3 = Wl[(kq*4+3)*64+fq];
      a0 += x0.x*w0 + x0.y*w1 + x0.z*w2 + x0.w*w3;
      a1 += x1.x*w0 + x1.y*w1 + x1.z*w2 + x1.w*w3;
      a2 += x2.x*w0 + x2.y*w1 + x2.z*w2 + x2.w*w3;
      a3 += x3.x*w0 + x3.y*w1 + x3.z*w2 + x3.w*w3;
    }
    vf4* Y = (vf4*)XW;
    Y[(size_t)n0*64 + fq]       = a0;
    Y[(size_t)n0*64 + 64 + fq]  = a1;
    Y[(size_t)n0*64 + 128 + fq] = a2;
    Y[(size_t)n0*64 + 192 + fq] = a3;
  }
}

// ---------------- LSTM part 2: recurrence (hh-half only) ----------------
// R12: R7-proven cooperative inner loop (quadrant weights in regs, h broadcast
// via LDS, 2 barriers/step), with three targeted fixes:
//  (a) XW interleaved [n][ch][4 gates] -> ONE dwordx4 per node-step (was 4
//      strided dwords = 4 HBM-miss events);
//  (b) prefetch row t+1 at top of step t (~full-step distance > 900cy miss);
//  (c) one task per block, grid 12500 w/ early exit -> no quantization tail.
__global__ __launch_bounds__(256) void k_rec(const float* __restrict__ XW,
        const float* __restrict__ whh, const float* __restrict__ bsum,
        const int* __restrict__ mlist, const unsigned* __restrict__ scal,
        float* __restrict__ dst, int scatter){
  int M = (int)scal[0];
  if (M < 0 || M > NN) M = 0;          // defensive (rocprof replay poisons scal)
  int task = blockIdx.x;
  if (task*4 >= M) return;             // block-uniform early exit
  int w = threadIdx.x>>6, lane = threadIdx.x&63;
  int r = w*64 + lane;
  const vf4* g4 = (const vf4*)&whh[(size_t)r*64];
  vf4 wh[16];
  #pragma unroll
  for (int j=0;j<16;j++) wh[j] = g4[j];
  __shared__ float sh[4][64];
  __shared__ float gates[4][4][64];
  int m = task*4 + w;
  bool valid = (m < M);
  int node = mlist[valid ? m : (M-1)];
  node = min(max(node, 0), NN-1);      // defensive vs poisoned mlist in replay
  const vf4* XW4 = (const vf4*)XW;
  vf4 bp = ((const vf4*)bsum)[lane];
  // prefetch rows 0 and 1 up front; row t+1 issued at top of step t
  vf4 xs0, xs1, xs2, xs3, xs4;
  {
    int r0 = node - 4, r1 = node - 3;
    xs0 = (r0 >= 0) ? XW4[(size_t)r0*64 + lane] : bp;
    xs1 = (r1 >= 0) ? XW4[(size_t)r1*64 + lane] : bp;
  }
  float c, h;
  {   // t = 0: h==0, gates = XW row (bias-only if left-padded)
    c = sigm(xs0.x)*ftanh(xs0.z);
    h = sigm(xs0.w)*ftanh(c);
    sh[w][lane] = h;
  }
  __syncthreads();
  #pragma unroll
  for (int t=1;t<SEQL;t++){
    // prefetch row t+1 (one full step of latency cover)
    if (t==1){ int ri = node-2; xs2 = (ri>=0) ? XW4[(size_t)ri*64+lane] : bp; }
    if (t==2){ int ri = node-1; xs3 = (ri>=0) ? XW4[(size_t)ri*64+lane] : bp; }
    if (t==3){ xs4 = XW4[(size_t)node*64 + lane]; }
    vf4 a0={0,0,0,0}, a1={0,0,0,0}, a2={0,0,0,0}, a3={0,0,0,0};
    #pragma unroll
    for (int j=0;j<16;j++){
      vf4 wj = wh[j];
      a0 += (*(const vf4*)&sh[0][j*4]) * wj;
      a1 += (*(const vf4*)&sh[1][j*4]) * wj;
      a2 += (*(const vf4*)&sh[2][j*4]) * wj;
      a3 += (*(const vf4*)&sh[3][j*4]) * wj;
    }
    gates[0][w][lane] = a0.x+a0.y+a0.z+a0.w;
    gates[1][w][lane] = a1.x+a1.y+a1.z+a1.w;
    gates[2][w][lane] = a2.x+a2.y+a2.z+a2.w;
    gates[3][w][lane] = a3.x+a3.y+a3.z+a3.w;
    __syncthreads();
    vf4 xv = (t==1) ? xs1 : (t==2) ? xs2 : (t==3) ? xs3 : xs4;
    float gi = gates[w][0][lane] + xv.x;
    float gf = gates[w][1][lane] + xv.y;
    float gg = gates[w][2][lane] + xv.z;
    float go = gates[w][3][lane] + xv.w;
    c = sigm(gf)*c + sigm(gi)*ftanh(gg);
    h = sigm(go)*ftanh(c);
    sh[w][lane] = h;
    __syncthreads();
  }
  if (valid){
    size_t o = scatter ? ((size_t)node*64 + lane) : ((size_t)m*64 + lane);
    dst[o] = h;
  }
}

// ==========================================================================
extern "C" void kernel_launch(void* const* d_in, const int* in_sizes, int n_in,
                              void* d_out, int out_size, void* d_ws, size_t ws_size,
                              hipStream_t stream) {
  const float* x   = (const float*)d_in[0];
  const int*   ei  = (const int*)d_in[1];
  const int*   row = ei;
  const int*   col = ei + EE;
  const void*  mp  = d_in[2];
  const float* W0  = (const float*)d_in[3];
  const float* b0  = (const float*)d_in[4];
  const float* W1  = (const float*)d_in[5];
  const float* b1  = (const float*)d_in[6];
  const float* pw  = (const float*)d_in[7];
  const float* Wu  = (const float*)d_in[8];
  const float* bu  = (const float*)d_in[9];
  const float* l0wih=(const float*)d_in[10];
  const float* l0whh=(const float*)d_in[11];
  const float* l0bih=(const float*)d_in[12];
  const float* l0bhh=(const float*)d_in[13];
  const float* lfwih=(const float*)d_in[14];
  const float* lfwhh=(const float*)d_in[15];
  const float* lfbih=(const float*)d_in[16];
  const float* lfbhh=(const float*)d_in[17];

  char* wp = (char*)d_ws;
  auto alloc = [&](size_t bytes)->char*{ char* p = wp; wp += ((bytes+255)/256)*256; return p; };
  float* A     = (float*)alloc((size_t)NN*64*4);   // h0 -> t2
  float* B     = (float*)alloc((size_t)NN*64*4);   // xo
  float* C     = (float*)alloc((size_t)NN*64*4);   // x1
  float* D     = (float*)alloc((size_t)NN*64*4);   // y
  float* Ebuf  = (float*)alloc((size_t)NN*64*4);   // hp -> up-GCN input
  float* Hbuf  = (float*)alloc((size_t)NN*64*4);   // LSTM0 compact output
  float* XW    = (float*)alloc((size_t)NN*256*4);  // gate-x precompute (51.2 MB)
  float* WT0   = (float*)alloc((size_t)256*64*4);
  float* WTf   = (float*)alloc((size_t)256*64*4);
  float* bs0   = (float*)alloc((size_t)256*4);
  float* bsf   = (float*)alloc((size_t)256*4);
  float* score = (float*)alloc((size_t)NN*4);
  float* dinv0 = (float*)alloc((size_t)NN*4);
  float* dinv1 = (float*)alloc((size_t)NN*4);
  unsigned long long* keys = (unsigned long long*)alloc((size_t)NN*8);
  int* degcnt  = (int*)alloc((size_t)NN*4);
  int* diagint = (int*)alloc((size_t)NN*4);
  int* ts      = (int*)alloc((size_t)NN*4);
  int* kp      = (int*)alloc((size_t)NN*4);
  int* mlist   = (int*)alloc((size_t)NN*4);
  int* minv    = (int*)alloc((size_t)NN*4);
  int* indptr  = (int*)alloc((size_t)(NN+1)*4);
  int* part    = (int*)alloc((size_t)NN*4);
  int* fillc   = (int*)alloc((size_t)NN*4);
  int* bsum    = (int*)alloc((size_t)256*4);
  int* csr_r   = (int*)alloc((size_t)EE*4);
  uint2* hash  = (uint2*)alloc((size_t)HASH_SIZE*8);
  unsigned* hist=(unsigned*)alloc((size_t)4*65536*4);
  unsigned* scal=(unsigned*)alloc(256);
  unsigned long long* selp = (unsigned long long*)(scal + 4);

  #define GRID1(n) dim3(((n)+255)/256), dim3(256), 0, stream
  #define GRIDW dim3((NN+3)/4), dim3(256), 0, stream

  // 1. merged init (hash, hist, per-node arrays, scalars, LSTM weight prep)
  k_init<<<GRID1(HASH_SIZE)>>>(hash, hist, degcnt, diagint, fillc, minv,
                               scal, selp, l0wih, l0bih, l0bhh, lfwih, lfbih, lfbhh,
                               WT0, WTf, bs0, bsf);
  // 2. degcnt + hash build + mask detect + GCN0 matmul (merged)
  k_phase2<<<GRID1(NN*16)>>>(row, col, (const int*)mp, degcnt, hash, scal, x, W0, A);
  // 3-4. indptr prefix sum (+dinv0); psum3 self-computes block offsets
  k_psum1<<<dim3(PSB),dim3(256),0,stream>>>(degcnt, part, bsum, dinv0);
  k_psum3<<<dim3(PSB),dim3(256),0,stream>>>(part, bsum, indptr);
  // 5. csr fill + A^2 diag + mask compact
  k_phase4<<<GRID1(EE+NN)>>>(row, col, indptr, fillc, csr_r, hash, diagint, mp, scal, mlist, minv);

  // GCN0 gather (+ fused TopK score/key + radix round-0 hist)
  g_gcn0<<<GRIDW>>>(indptr, csr_r, dinv0, A, b0, pw, C, keys, score, hist);

  // TopK radix select (round-0 hist already done)
  k_pick<<<dim3(1),dim3(256),0,stream>>>(hist, selp, scal);
  for (int r2=1;r2<4;r2++){
    k_hist<<<GRID1(NN)>>>(keys, hist + r2*65536, selp, r2);
    k_pick<<<dim3(1),dim3(256),0,stream>>>(hist + r2*65536, selp, scal);
  }
  // pooled degree pass 1, then pass2+dinv1 merged with hp matmul
  k_tsg<<<GRID1(NN)>>>(indptr, csr_r, keys, selp, kp, ts);
  k_csgmm<<<GRID1(NN*16+NN)>>>(indptr, csr_r, ts, diagint, kp, dinv1, C, W1, score, Ebuf);
  g_t2<<<GRIDW>>>(indptr, csr_r, dinv1, Ebuf, A);

  // LSTM0 on x1 windows -> Hbuf (compact)
  k_xw<<<dim3(512),dim3(256),0,stream>>>(C, WT0, bs0, XW);
  k_rec<<<dim3(12500),dim3(256),0,stream>>>(XW, l0whh, bs0, mlist, scal, Hbuf, 0);

  // y = res + up (fused: base select + relu(x2))
  g_agg2y<<<GRIDW>>>(indptr, csr_r, A, Ebuf, dinv1, diagint, kp, b1, C, Hbuf, minv, D);

  // up-GCN -> xo (B) and d_out
  k_mm64v<<<GRID1(NN*16)>>>(D, Wu, Ebuf);
  g_up<<<GRIDW>>>(indptr, csr_r, dinv0, Ebuf, bu, B, (float*)d_out);

  // final LSTM on xo windows, scatter into d_out masked rows
  k_xw<<<dim3(512),dim3(256),0,stream>>>(B, WTf, bsf, XW);
  k_rec<<<dim3(12500),dim3(256),0,stream>>>(XW, lfwhh, bsf, mlist, scal, (float*)d_out, 1);
  #undef GRIDW
  #undef GRID1
}